// Round 5
// baseline (494.768 us; speedup 1.0000x reference)
//
#include <hip/hip_runtime.h>

#define EPS 1e-5f

constexpr int NB   = 8;
constexpr int NN   = 2048;
constexpr int DIM  = 128;
constexpr int KNN  = 16;
constexpr int AH   = 512;
constexpr int NPTS = NB * NN;
constexpr float SCALE = 0.08838834764831845f; // 1/sqrt(128)

typedef __attribute__((ext_vector_type(8))) short short8;
typedef __attribute__((ext_vector_type(4))) float floatx4;

// round-half-up bf16 conversion: 2 VALU ops (vs 5 for full RNE); threshold
// headroom is ~6x and ties are rare — measured absmax stays well under.
__device__ __forceinline__ short f2bf(float f) {
  union { float f; unsigned u; } a; a.f = f;
  return (short)((a.u + 0x8000u) >> 16);
}
__device__ __forceinline__ float bf2f(short s) {
  union { unsigned u; float f; } a; a.u = ((unsigned)(unsigned short)s) << 16;
  return a.f;
}

// ---------------------------------------------------------------------------
// fp32 tiled GEMM (only Wf = w_in @ w_qkv, tiny). 64x64 tile.
// ---------------------------------------------------------------------------
__global__ __launch_bounds__(256) void gemm_f32(
    const float* __restrict__ A, const float* __restrict__ W,
    float* __restrict__ C, int M, int N, int K)
{
  __shared__ float As[64][33];
  __shared__ float Ws[32][65];
  const int bm = blockIdx.x * 64, bn = blockIdx.y * 64;
  const int tid = threadIdx.x;
  const int tx = tid & 15, ty = tid >> 4;
  float acc[4][4] = {};
  for (int k0 = 0; k0 < K; k0 += 32) {
#pragma unroll
    for (int i = 0; i < 8; ++i) {
      int e = tid + i * 256;
      As[e >> 5][e & 31] = A[(size_t)(bm + (e >> 5)) * K + k0 + (e & 31)];
    }
#pragma unroll
    for (int i = 0; i < 8; ++i) {
      int e = tid + i * 256;
      Ws[e >> 6][e & 63] = W[(size_t)(k0 + (e >> 6)) * N + bn + (e & 63)];
    }
    __syncthreads();
#pragma unroll
    for (int kk = 0; kk < 32; ++kk) {
      float a[4], w[4];
#pragma unroll
      for (int i = 0; i < 4; ++i) a[i] = As[ty * 4 + i][kk];
#pragma unroll
      for (int j = 0; j < 4; ++j) w[j] = Ws[kk][tx * 4 + j];
#pragma unroll
      for (int i = 0; i < 4; ++i)
#pragma unroll
        for (int j = 0; j < 4; ++j)
          acc[i][j] += a[i] * w[j];
    }
    __syncthreads();
  }
#pragma unroll
  for (int i = 0; i < 4; ++i)
#pragma unroll
    for (int j = 0; j < 4; ++j)
      C[(size_t)(bm + ty * 4 + i) * N + bn + tx * 4 + j] = acc[i][j];
}

// ---------------------------------------------------------------------------
// KNN: one wave per point; 32 distances/lane in regs (SoA coalesced loads);
// 16 butterfly-argmin rounds; lowest-index tie-break. No LDS/barriers.
// ---------------------------------------------------------------------------
__global__ __launch_bounds__(256) void knn_kernel(
    const float* __restrict__ pos_t, int* __restrict__ idx_out)
{
  const int tid = threadIdx.x;
  const int lane = tid & 63;
  const int p = blockIdx.x * 4 + (tid >> 6);
  const int b = p >> 11, i = p & (NN - 1);
  const float* px = pos_t + (size_t)b * 3 * NN;
  const float* py = px + NN;
  const float* pz = py + NN;
  const float xi = px[i], yi = py[i], zi = pz[i];
  const float sqi = xi * xi + yi * yi + zi * zi;
  float v[32];
#pragma unroll
  for (int t = 0; t < 32; ++t) {
    int j = t * 64 + lane;
    float xj = px[j], yj = py[j], zj = pz[j];
    float sqj = xj * xj + yj * yj + zj * zj;
    float dot = xi * xj + yi * yj + zi * zj;
    v[t] = sqi + sqj - 2.0f * dot;
  }
  for (int s = 0; s < KNN; ++s) {
    float bv = 3.4e38f; int bj = 1 << 30;
#pragma unroll
    for (int t = 0; t < 32; ++t) {
      if (v[t] < bv) { bv = v[t]; bj = t * 64 + lane; }
    }
#pragma unroll
    for (int m = 1; m < 64; m <<= 1) {
      float ov = __shfl_xor(bv, m);
      int   oj = __shfl_xor(bj, m);
      if (ov < bv || (ov == bv && oj < bj)) { bv = ov; bj = oj; }
    }
    if (lane == 0) idx_out[(size_t)p * KNN + s] = bj;
#pragma unroll
    for (int t = 0; t < 32; ++t)
      if (bj == t * 64 + lane) v[t] = 3.4e38f;
  }
}

// ---------------------------------------------------------------------------
// Pack weights into bf16 B-fragment layouts (frag f at [f*512 + lane*8 + j],
// value = W[k = ks*32 + q*8 + j][n]) + folded BN + biases + pos SoA transpose.
// ---------------------------------------------------------------------------
__global__ __launch_bounds__(256) void pack_weights(
    const float* __restrict__ attn_w1, const float* __restrict__ attn_w2,
    const float* __restrict__ pos_w2, const float* __restrict__ Wf,
    const float* __restrict__ w_out, const float* __restrict__ pos,
    const float* __restrict__ attn_b1, const float* __restrict__ abn_g,
    const float* __restrict__ abn_b, const float* __restrict__ abn_m,
    const float* __restrict__ abn_v,
    const float* __restrict__ pos_b1, const float* __restrict__ pbn_g,
    const float* __restrict__ pbn_b, const float* __restrict__ pbn_m,
    const float* __restrict__ pbn_v, const float* __restrict__ pos_b2,
    short* __restrict__ w1p, short* __restrict__ w2p, short* __restrict__ pw2p,
    short* __restrict__ wfp, short* __restrict__ wop,
    float* __restrict__ biasq,
    float* __restrict__ t1sc, float* __restrict__ t1bi,
    float* __restrict__ phsc, float* __restrict__ phbi,
    float* __restrict__ pos_t)
{
  int t = blockIdx.x * 256 + threadIdx.x;
  if (t < 65536) {                       // w1p: [128x512], 8 chunks of 64 cols
    int j = t & 7, lane = (t >> 3) & 63, ks = (t >> 9) & 3, nt = (t >> 11) & 3, ch = t >> 13;
    int q = lane >> 4, cc = lane & 15;
    int k = ks * 32 + q * 8 + j, n = ch * 64 + nt * 16 + cc;
    w1p[t] = f2bf(attn_w1[(size_t)k * AH + n]);
  } else if (t < 131072) {               // w2p: [512x128], 8 chunks of 64 rows
    int e = t - 65536;
    int j = e & 7, lane = (e >> 3) & 63, ks = (e >> 9) & 1, nt = (e >> 10) & 7, ch = e >> 13;
    int q = lane >> 4, cc = lane & 15;
    int k = ch * 64 + ks * 32 + q * 8 + j, n = nt * 16 + cc;
    w2p[e] = f2bf(attn_w2[(size_t)k * DIM + n]);
  } else if (t < 139264) {               // pw2p: pos_w2 [64x128]
    int e = t - 131072;
    int j = e & 7, lane = (e >> 3) & 63, ks = (e >> 9) & 1, nt = e >> 10;
    int q = lane >> 4, cc = lane & 15;
    int k = ks * 32 + q * 8 + j, n = nt * 16 + cc;
    pw2p[e] = f2bf(pos_w2[(size_t)k * DIM + n]);
  } else if (t < 188416) {               // wfp: Wf [128x384], 3 col-chunks
    int e = t - 139264;
    int j = e & 7, lane = (e >> 3) & 63, ks = (e >> 9) & 3, nt = (e >> 11) & 7, nc = e >> 14;
    int q = lane >> 4, cc = lane & 15;
    int k = ks * 32 + q * 8 + j, n = nc * 128 + nt * 16 + cc;
    wfp[e] = f2bf(Wf[(size_t)k * 384 + n]);
  } else if (t < 204800) {               // wop: w_out [128x128]
    int e = t - 188416;
    int j = e & 7, lane = (e >> 3) & 63, ks = (e >> 9) & 3, nt = (e >> 11) & 7;
    int q = lane >> 4, cc = lane & 15;
    int k = ks * 32 + q * 8 + j, n = nt * 16 + cc;
    wop[e] = f2bf(w_out[(size_t)k * DIM + n]);
  } else if (t < 205184) {               // biasq[384]: pos_b2 into q,v cols
    int c = t - 204800;
    biasq[c] = (c < 128) ? pos_b2[c] : ((c < 256) ? 0.0f : pos_b2[c - 256]);
  } else if (t < 205696) {
    int c = t - 205184;
    t1sc[c] = abn_g[c] * rsqrtf(abn_v[c] + EPS);
  } else if (t < 206208) {
    int c = t - 205696;
    float sc = abn_g[c] * rsqrtf(abn_v[c] + EPS);
    t1bi[c] = (attn_b1[c] - abn_m[c]) * sc + abn_b[c];
  } else if (t < 206272) {
    int c = t - 206208;
    phsc[c] = pbn_g[c] * rsqrtf(pbn_v[c] + EPS);
  } else if (t < 206336) {
    int c = t - 206272;
    float sc = pbn_g[c] * rsqrtf(pbn_v[c] + EPS);
    phbi[c] = (pos_b1[c] - pbn_m[c]) * sc + pbn_b[c];
  } else if (t < 206336 + NPTS * 3) {    // pos -> SoA pos_t[b][3][NN]
    int e = t - 206336;
    int p = e / 3, d = e - p * 3;
    int b = p >> 11, n = p & (NN - 1);
    pos_t[((size_t)b * 3 + d) * NN + n] = pos[e];
  }
}

// ---------------------------------------------------------------------------
// MFMA GEMM: qkv[16384x384] (bf16 out) = bf16(ori_x) @ wfp + biasq.
// M=64 blocks; 3 col-chunks looped inside (A staged once).
// ---------------------------------------------------------------------------
__global__ __launch_bounds__(256, 4) void gemm_in(
    const float* __restrict__ A, const short* __restrict__ wfp,
    const float* __restrict__ biasq, short* __restrict__ C)
{
  __shared__ short As[64 * 128];
  const int tid = threadIdx.x;
  const int lane = tid & 63, w = tid >> 6;
  const int wr = w >> 1, wc = w & 1;
  const int q = lane >> 4, cc = lane & 15;
  const int row0 = blockIdx.x * 64;
#pragma unroll
  for (int it = 0; it < 4; ++it) {
    int e = tid + it * 256;
    int row = e >> 4, cg = e & 15;
    const float* src = A + (size_t)(row0 + row) * 128 + cg * 8;
    float4 f0 = *(const float4*)src, f1 = *(const float4*)(src + 4);
    short8 v;
    v[0] = f2bf(f0.x); v[1] = f2bf(f0.y); v[2] = f2bf(f0.z); v[3] = f2bf(f0.w);
    v[4] = f2bf(f1.x); v[5] = f2bf(f1.y); v[6] = f2bf(f1.z); v[7] = f2bf(f1.w);
    *(short8*)(As + row * 128 + ((cg ^ (row & 15)) << 3)) = v;
  }
  __syncthreads();
  for (int nc = 0; nc < 3; ++nc) {
    floatx4 acc[2][4];
#pragma unroll
    for (int i = 0; i < 2; ++i)
#pragma unroll
      for (int jt = 0; jt < 4; ++jt) acc[i][jt] = (floatx4){0.f, 0.f, 0.f, 0.f};
#pragma unroll
    for (int ks = 0; ks < 4; ++ks) {
      short8 a8[2], b8[4];
#pragma unroll
      for (int i = 0; i < 2; ++i) {
        int row = (wr * 2 + i) * 16 + cc;
        a8[i] = *(const short8*)(As + row * 128 + (((ks * 4 + q) ^ cc) << 3));
      }
#pragma unroll
      for (int jt = 0; jt < 4; ++jt)
        b8[jt] = *(const short8*)(wfp + ((((nc * 8 + wc * 4 + jt) * 4 + ks) * 64 + lane) << 3));
#pragma unroll
      for (int i = 0; i < 2; ++i)
#pragma unroll
        for (int jt = 0; jt < 4; ++jt)
          acc[i][jt] = __builtin_amdgcn_mfma_f32_16x16x32_bf16(a8[i], b8[jt], acc[i][jt], 0, 0, 0);
    }
#pragma unroll
    for (int jt = 0; jt < 4; ++jt) {
      int colG = nc * 128 + (wc * 4 + jt) * 16 + cc;
      float bv = biasq[colG];
#pragma unroll
      for (int i = 0; i < 2; ++i)
#pragma unroll
        for (int r = 0; r < 4; ++r) {
          int row = (wr * 2 + i) * 16 + q * 4 + r;
          C[(size_t)(row0 + row) * 384 + colG] = f2bf(acc[i][jt][r] + bv);
        }
    }
  }
}

// ---------------------------------------------------------------------------
// MFMA GEMM: out[16384x128] = bf16(agg) @ wop + ori_x. M=64 blocks.
// ---------------------------------------------------------------------------
__global__ __launch_bounds__(256, 4) void gemm_out(
    const float* __restrict__ A, const short* __restrict__ wop,
    const float* __restrict__ R, float* __restrict__ C)
{
  __shared__ short As[64 * 128];
  const int tid = threadIdx.x;
  const int lane = tid & 63, w = tid >> 6;
  const int wr = w >> 1, wc = w & 1;
  const int q = lane >> 4, cc = lane & 15;
  const int row0 = blockIdx.x * 64;
#pragma unroll
  for (int it = 0; it < 4; ++it) {
    int e = tid + it * 256;
    int row = e >> 4, cg = e & 15;
    const float* src = A + (size_t)(row0 + row) * 128 + cg * 8;
    float4 f0 = *(const float4*)src, f1 = *(const float4*)(src + 4);
    short8 v;
    v[0] = f2bf(f0.x); v[1] = f2bf(f0.y); v[2] = f2bf(f0.z); v[3] = f2bf(f0.w);
    v[4] = f2bf(f1.x); v[5] = f2bf(f1.y); v[6] = f2bf(f1.z); v[7] = f2bf(f1.w);
    *(short8*)(As + row * 128 + ((cg ^ (row & 15)) << 3)) = v;
  }
  __syncthreads();
  floatx4 acc[2][4];
#pragma unroll
  for (int i = 0; i < 2; ++i)
#pragma unroll
    for (int jt = 0; jt < 4; ++jt) acc[i][jt] = (floatx4){0.f, 0.f, 0.f, 0.f};
#pragma unroll
  for (int ks = 0; ks < 4; ++ks) {
    short8 a8[2], b8[4];
#pragma unroll
    for (int i = 0; i < 2; ++i) {
      int row = (wr * 2 + i) * 16 + cc;
      a8[i] = *(const short8*)(As + row * 128 + (((ks * 4 + q) ^ cc) << 3));
    }
#pragma unroll
    for (int jt = 0; jt < 4; ++jt)
      b8[jt] = *(const short8*)(wop + ((((wc * 4 + jt) * 4 + ks) * 64 + lane) << 3));
#pragma unroll
    for (int i = 0; i < 2; ++i)
#pragma unroll
      for (int jt = 0; jt < 4; ++jt)
        acc[i][jt] = __builtin_amdgcn_mfma_f32_16x16x32_bf16(a8[i], b8[jt], acc[i][jt], 0, 0, 0);
  }
#pragma unroll
  for (int jt = 0; jt < 4; ++jt) {
    int col = (wc * 4 + jt) * 16 + cc;
#pragma unroll
    for (int i = 0; i < 2; ++i)
#pragma unroll
      for (int r = 0; r < 4; ++r) {
        int row = (wr * 2 + i) * 16 + q * 4 + r;
        size_t o = (size_t)(row0 + row) * 128 + col;
        C[o] = acc[i][jt][r] + R[o];
      }
  }
}

// ---------------------------------------------------------------------------
// Fused MFMA attention: 4 points/block (M=64), 4 waves each 32 rows.
// BARRIER-FREE main loop: each wave computes the FULL 64-col t1 tile for its
// own 32 rows into a wave-PRIVATE LDS tile t1p[w] (within-wave LDS ordering
// is compiler-handled lgkmcnt, no __syncthreads). GEMM1 MFMAs double
// (128->256/wave) but all 16 main-loop barriers disappear. Occupancy is
// reg-limited at 3 blocks/CU (unified VGPR+AGPR ~150/thread; measured 31%
// across LDS 51.7/35.3/27.1 KB), so the LDS growth to ~34.6 KB is free.
//   ph (relp@pos_w1) is staged in av_s (free pre-combine); pe reads it, then
//   (after a barrier) combine overwrites av_s with the GEMM1 A-matrix;
//   A-fragments are chunk-invariant -> hoisted to af[2][4] regs; av_s is then
//   reused to park vpe = v_g + pe (thread-local slots).
// launch_bounds (256,3): the (256,4) 128-reg cap caused a 300MB scratch
// spill (rounds 1-2); cap ~170 fits cleanly.
// XCD-affinity: batch = blockIdx.x & 7.
// ---------------------------------------------------------------------------
__global__ __launch_bounds__(256, 3) void fused_attn(
    const float* __restrict__ pos, const short* __restrict__ qkv,
    const int* __restrict__ knn_idx,
    const float* __restrict__ pos_w1,
    const short* __restrict__ w1p, const short* __restrict__ w2p,
    const short* __restrict__ pw2p,
    const float* __restrict__ t1sc, const float* __restrict__ t1bi,
    const float* __restrict__ phsc, const float* __restrict__ phbi,
    const float* __restrict__ attn_b2,
    float* __restrict__ agg)
{
  __shared__ short av_s[64 * 128];      // 16 KB: ph (64x64), then a, then vpe
  __shared__ short t1p[4][32 * 64];     // 16 KB: per-wave private t1 tiles
  __shared__ short q_ss[4 * 128];       // 1 KB bf16 q rows
  __shared__ float relp_s[64 * 4];
  __shared__ int   nbr_s[64];

  const int tid = threadIdx.x;
  const int lane = tid & 63, w = tid >> 6;
  const int wr = w >> 1, wc = w & 1;
  const int q = lane >> 4, cc = lane & 15;
  const int bb = blockIdx.x & 7;                     // XCD-affinity swizzle
  const int gp0 = bb * NN + (blockIdx.x >> 3) * 4;   // 4 points/block

  if (tid < 64) nbr_s[tid] = knn_idx[(size_t)gp0 * KNN + tid];
  if (tid >= 64 && tid < 128) {  // stage q rows (bf16)
    int e = tid - 64;
    int p = e >> 4, seg = e & 15;
    *(short8*)(q_ss + p * 128 + seg * 8) =
        *(const short8*)(qkv + (size_t)(gp0 + p) * 384 + seg * 8);
  }
  __syncthreads();
  if (tid < 64) {
    int p = tid >> 4;
    int j = nbr_s[tid];
    const float* pa = pos + (size_t)(gp0 + p) * 3;
    const float* pj = pos + ((size_t)bb * NN + j) * 3;
    relp_s[tid * 4 + 0] = pa[0] - pj[0];
    relp_s[tid * 4 + 1] = pa[1] - pj[1];
    relp_s[tid * 4 + 2] = pa[2] - pj[2];
  }
  __syncthreads();

  // ph = relu(bn(relp @ pos_w1 + b1)) -> av_s as 64x64 (swizzle on row&7)
#pragma unroll
  for (int r2 = 0; r2 < 16; ++r2) {
    int e = tid + r2 * 256;
    int row = e >> 6, c = e & 63;
    float lin = relp_s[row * 4] * pos_w1[c] + relp_s[row * 4 + 1] * pos_w1[64 + c]
              + relp_s[row * 4 + 2] * pos_w1[128 + c];
    av_s[row * 64 + (((c >> 3) ^ (row & 7)) << 3) + (c & 7)] =
        f2bf(fmaxf(lin * phsc[c] + phbi[c], 0.0f));
  }
  __syncthreads();

  // pe = ph @ pos_w2 (pos_b2 pre-folded into qkv q/v cols)
  floatx4 pe[2][4];
#pragma unroll
  for (int i = 0; i < 2; ++i)
#pragma unroll
    for (int jt = 0; jt < 4; ++jt) pe[i][jt] = (floatx4){0.f, 0.f, 0.f, 0.f};
#pragma unroll
  for (int ks = 0; ks < 2; ++ks) {
    short8 a8[2];
#pragma unroll
    for (int i = 0; i < 2; ++i) {
      int row = (wr * 2 + i) * 16 + cc;
      a8[i] = *(const short8*)(av_s + row * 64 + (((ks * 4 + q) ^ (row & 7)) << 3));
    }
#pragma unroll
    for (int jt = 0; jt < 4; ++jt) {
      short8 b8 = *(const short8*)(pw2p + ((((wc * 4 + jt) * 2 + ks) * 64 + lane) << 3));
#pragma unroll
      for (int i = 0; i < 2; ++i)
        pe[i][jt] = __builtin_amdgcn_mfma_f32_16x16x32_bf16(a8[i], b8, pe[i][jt], 0, 0, 0);
    }
  }
  __syncthreads();   // all ph reads done before combine overwrites av_s

  // preload q values for this thread's (row-tile, col) positions
  float qreg[2][4];
#pragma unroll
  for (int i = 0; i < 2; ++i)
#pragma unroll
    for (int jt = 0; jt < 4; ++jt)
      qreg[i][jt] = bf2f(q_ss[(wr * 2 + i) * 128 + (wc * 4 + jt) * 16 + cc]);

  // combine: a = q - k_g + pe -> av_s (64x128) ; vpe = v_g + pe -> regs.
  floatx4 vpe[2][4];
#pragma unroll
  for (int i = 0; i < 2; ++i) {
    int rt = wr * 2 + i;
#pragma unroll
    for (int r = 0; r < 4; ++r) {
      int row = rt * 16 + q * 4 + r;
      const short* kv = qkv + ((size_t)bb * NN + nbr_s[row]) * 384;
      int sb = row * 128, sx = row & 15;
#pragma unroll
      for (int jt = 0; jt < 4; ++jt) {
        int col = (wc * 4 + jt) * 16 + cc;
        float pev = pe[i][jt][r];
        av_s[sb + (((col >> 3) ^ sx) << 3) + (col & 7)] =
            f2bf(qreg[i][jt] - bf2f(kv[128 + col]) + pev);
        vpe[i][jt][r] = bf2f(kv[256 + col]) + pev;
      }
    }
  }
  __syncthreads();   // av_s (=a) fully built

  // Hoist chunk-invariant A-fragments into registers (used every chunk).
  short8 af[2][4];
#pragma unroll
  for (int i = 0; i < 2; ++i) {
    int row = (wr * 2 + i) * 16 + cc;
#pragma unroll
    for (int ks = 0; ks < 4; ++ks)
      af[i][ks] = *(const short8*)(av_s + row * 128 + (((ks * 4 + q) ^ cc) << 3));
  }
  __syncthreads();   // all a-frags consumed; av_s reusable

  // Park vpe into av_s (thread-local slots; same thread reads them back).
#pragma unroll
  for (int i = 0; i < 2; ++i) {
    int rt = wr * 2 + i;
#pragma unroll
    for (int r = 0; r < 4; ++r) {
      int row = rt * 16 + q * 4 + r;
      int sb = row * 128, sx = row & 15;
#pragma unroll
      for (int jt = 0; jt < 4; ++jt) {
        int col = (wc * 4 + jt) * 16 + cc;
        av_s[sb + (((col >> 3) ^ sx) << 3) + (col & 7)] = f2bf(vpe[i][jt][r]);
      }
    }
  }

  floatx4 hacc[2][4];
#pragma unroll
  for (int i = 0; i < 2; ++i)
#pragma unroll
    for (int jt = 0; jt < 4; ++jt) hacc[i][jt] = (floatx4){0.f, 0.f, 0.f, 0.f};

  short* t1w = t1p[w];   // wave-private 32x64 tile

  for (int ch = 0; ch < 8; ++ch) {
    // GEMM1: full 64-col t1 tile for this wave's 32 rows (A from registers)
    floatx4 tacc[2][4];
#pragma unroll
    for (int i = 0; i < 2; ++i)
#pragma unroll
      for (int jt = 0; jt < 4; ++jt) tacc[i][jt] = (floatx4){0.f, 0.f, 0.f, 0.f};
#pragma unroll
    for (int ks = 0; ks < 4; ++ks) {
      short8 b8[4];
#pragma unroll
      for (int jt = 0; jt < 4; ++jt)
        b8[jt] = *(const short8*)(w1p + ((((ch * 4 + jt) * 4 + ks) * 64 + lane) << 3));
#pragma unroll
      for (int i = 0; i < 2; ++i)
#pragma unroll
        for (int jt = 0; jt < 4; ++jt)
          tacc[i][jt] = __builtin_amdgcn_mfma_f32_16x16x32_bf16(af[i][ks], b8[jt], tacc[i][jt], 0, 0, 0);
    }
    // bn/relu -> t1w (local rows 0..31, swizzle on lrow&7)
#pragma unroll
    for (int jt = 0; jt < 4; ++jt) {
      int colL = jt * 16 + cc;
      int colG = ch * 64 + colL;
      float sc = t1sc[colG], bi = t1bi[colG];
#pragma unroll
      for (int i = 0; i < 2; ++i)
#pragma unroll
        for (int r = 0; r < 4; ++r) {
          int lrow = i * 16 + q * 4 + r;
          t1w[lrow * 64 + (((colL >> 3) ^ (lrow & 7)) << 3) + (colL & 7)] =
              f2bf(fmaxf(tacc[i][jt][r] * sc + bi, 0.0f));
        }
    }
    // GEMM2: hacc += t1 @ w2[ch*64 : +64, :]  (reads own tile; no barrier)
#pragma unroll
    for (int ks = 0; ks < 2; ++ks) {
      short8 a8[2], b8[4];
#pragma unroll
      for (int i = 0; i < 2; ++i) {
        int lrow = i * 16 + cc;
        a8[i] = *(const short8*)(t1w + lrow * 64 + (((ks * 4 + q) ^ (lrow & 7)) << 3));
      }
#pragma unroll
      for (int jt = 0; jt < 4; ++jt)
        b8[jt] = *(const short8*)(w2p + ((((ch * 8 + wc * 4 + jt) * 2 + ks) * 64 + lane) << 3));
#pragma unroll
      for (int i = 0; i < 2; ++i)
#pragma unroll
        for (int jt = 0; jt < 4; ++jt)
          hacc[i][jt] = __builtin_amdgcn_mfma_f32_16x16x32_bf16(a8[i], b8[jt], hacc[i][jt], 0, 0, 0);
    }
  }

  // softmax over the 16 neighbors per (point, channel) + aggregate
#pragma unroll
  for (int i = 0; i < 2; ++i) {
    int rt = wr * 2 + i;
#pragma unroll
    for (int jt = 0; jt < 4; ++jt) {
      int col = (wc * 4 + jt) * 16 + cc;
      float b2v = attn_b2[col];
      float v0[4], mx = -3.4e38f;
#pragma unroll
      for (int r = 0; r < 4; ++r) {
        v0[r] = (hacc[i][jt][r] + b2v) * SCALE;
        mx = fmaxf(mx, v0[r]);
      }
      mx = fmaxf(mx, __shfl_xor(mx, 16));
      mx = fmaxf(mx, __shfl_xor(mx, 32));
      float ex[4], sum = 0.f;
#pragma unroll
      for (int r = 0; r < 4; ++r) { ex[r] = __expf(v0[r] - mx); sum += ex[r]; }
      sum += __shfl_xor(sum, 16);
      sum += __shfl_xor(sum, 32);
      float inv = 1.0f / sum;
      float part = 0.f;
#pragma unroll
      for (int r = 0; r < 4; ++r) {
        int row = rt * 16 + q * 4 + r;
        int slot = row * 128 + (((col >> 3) ^ (row & 15)) << 3) + (col & 7);
        part += ex[r] * bf2f(av_s[slot]);
      }
      part += __shfl_xor(part, 16);
      part += __shfl_xor(part, 32);
      if (q == 0) agg[(size_t)(gp0 + rt) * DIM + col] = part * inv;
    }
  }
}

extern "C" void kernel_launch(void* const* d_in, const int* in_sizes, int n_in,
                              void* d_out, int out_size, void* d_ws, size_t ws_size,
                              hipStream_t stream)
{
  const float* ori_x    = (const float*)d_in[0];
  const float* pos      = (const float*)d_in[1];
  const float* w_in     = (const float*)d_in[2];
  const float* w_qkv    = (const float*)d_in[3];
  const float* w_out    = (const float*)d_in[4];
  const float* pos_w1   = (const float*)d_in[5];
  const float* pos_b1   = (const float*)d_in[6];
  const float* pos_bn_g = (const float*)d_in[7];
  const float* pos_bn_b = (const float*)d_in[8];
  const float* pos_bn_m = (const float*)d_in[9];
  const float* pos_bn_v = (const float*)d_in[10];
  const float* pos_w2   = (const float*)d_in[11];
  const float* pos_b2   = (const float*)d_in[12];
  const float* attn_w1  = (const float*)d_in[13];
  const float* attn_b1  = (const float*)d_in[14];
  const float* attn_bn_g = (const float*)d_in[15];
  const float* attn_bn_b = (const float*)d_in[16];
  const float* attn_bn_m = (const float*)d_in[17];
  const float* attn_bn_v = (const float*)d_in[18];
  const float* attn_w2  = (const float*)d_in[19];
  const float* attn_b2  = (const float*)d_in[20];
  float* out = (float*)d_out;

  float* agg  = (float*)d_ws;                          // [NPTS*128] f32; Wf aliases head
  float* Wf   = agg;                                   // [128*384] (consumed by pack)
  short* qkvb = (short*)(agg + (size_t)NPTS * DIM);    // [NPTS*384] bf16
  int*   idx  = (int*)(qkvb + (size_t)NPTS * 3 * DIM); // [NPTS*16]
  short* w1p  = (short*)(idx + (size_t)NPTS * KNN);
  short* w2p  = w1p + 65536;
  short* pw2p = w2p + 65536;
  short* wfp  = pw2p + 8192;
  short* wop  = wfp + 49152;
  float* biasq = (float*)(wop + 16384);
  float* t1sc = biasq + 384;
  float* t1bi = t1sc + 512;
  float* phsc = t1bi + 512;
  float* phbi = phsc + 64;
  float* pos_t = phbi + 64;                            // [NB*3*NN]

  gemm_f32<<<dim3(2, 6), 256, 0, stream>>>(w_in, w_qkv, Wf, 128, 384, 128);
  pack_weights<<<998, 256, 0, stream>>>(attn_w1, attn_w2, pos_w2, Wf, w_out, pos,
      attn_b1, attn_bn_g, attn_bn_b, attn_bn_m, attn_bn_v,
      pos_b1, pos_bn_g, pos_bn_b, pos_bn_m, pos_bn_v, pos_b2,
      w1p, w2p, pw2p, wfp, wop, biasq, t1sc, t1bi, phsc, phbi, pos_t);
  gemm_in<<<NPTS / 64, 256, 0, stream>>>(ori_x, wfp, biasq, qkvb);
  knn_kernel<<<NPTS / 4, 256, 0, stream>>>(pos_t, idx);
  fused_attn<<<NPTS / 4, 256, 0, stream>>>(pos, qkvb, idx, pos_w1,
      w1p, w2p, pw2p, t1sc, t1bi, phsc, phbi, attn_b2, agg);
  gemm_out<<<NPTS / 64, 256, 0, stream>>>(agg, wop, ori_x, out);
}

// Round 6
// 416.333 us; speedup vs baseline: 1.1884x; 1.1884x over previous
//
#include <hip/hip_runtime.h>

#define EPS 1e-5f

constexpr int NB   = 8;
constexpr int NN   = 2048;
constexpr int DIM  = 128;
constexpr int KNN  = 16;
constexpr int AH   = 512;
constexpr int NPTS = NB * NN;
constexpr float SCALE = 0.08838834764831845f; // 1/sqrt(128)

typedef __attribute__((ext_vector_type(8))) short short8;
typedef __attribute__((ext_vector_type(4))) float floatx4;

// round-half-up bf16 conversion: 2 VALU ops (vs 5 for full RNE); threshold
// headroom is ~6x and ties are rare — measured absmax stays well under.
__device__ __forceinline__ short f2bf(float f) {
  union { float f; unsigned u; } a; a.f = f;
  return (short)((a.u + 0x8000u) >> 16);
}
__device__ __forceinline__ float bf2f(short s) {
  union { unsigned u; float f; } a; a.u = ((unsigned)(unsigned short)s) << 16;
  return a.f;
}

// ---------------------------------------------------------------------------
// fp32 tiled GEMM (only Wf = w_in @ w_qkv, tiny). 64x64 tile.
// ---------------------------------------------------------------------------
__global__ __launch_bounds__(256) void gemm_f32(
    const float* __restrict__ A, const float* __restrict__ W,
    float* __restrict__ C, int M, int N, int K)
{
  __shared__ float As[64][33];
  __shared__ float Ws[32][65];
  const int bm = blockIdx.x * 64, bn = blockIdx.y * 64;
  const int tid = threadIdx.x;
  const int tx = tid & 15, ty = tid >> 4;
  float acc[4][4] = {};
  for (int k0 = 0; k0 < K; k0 += 32) {
#pragma unroll
    for (int i = 0; i < 8; ++i) {
      int e = tid + i * 256;
      As[e >> 5][e & 31] = A[(size_t)(bm + (e >> 5)) * K + k0 + (e & 31)];
    }
#pragma unroll
    for (int i = 0; i < 8; ++i) {
      int e = tid + i * 256;
      Ws[e >> 6][e & 63] = W[(size_t)(k0 + (e >> 6)) * N + bn + (e & 63)];
    }
    __syncthreads();
#pragma unroll
    for (int kk = 0; kk < 32; ++kk) {
      float a[4], w[4];
#pragma unroll
      for (int i = 0; i < 4; ++i) a[i] = As[ty * 4 + i][kk];
#pragma unroll
      for (int j = 0; j < 4; ++j) w[j] = Ws[kk][tx * 4 + j];
#pragma unroll
      for (int i = 0; i < 4; ++i)
#pragma unroll
        for (int j = 0; j < 4; ++j)
          acc[i][j] += a[i] * w[j];
    }
    __syncthreads();
  }
#pragma unroll
  for (int i = 0; i < 4; ++i)
#pragma unroll
    for (int j = 0; j < 4; ++j)
      C[(size_t)(bm + ty * 4 + i) * N + bn + tx * 4 + j] = acc[i][j];
}

// ---------------------------------------------------------------------------
// KNN: one wave per point; 32 distances/lane in regs (SoA coalesced loads);
// 16 butterfly-argmin rounds; lowest-index tie-break. No LDS/barriers.
// ---------------------------------------------------------------------------
__global__ __launch_bounds__(256) void knn_kernel(
    const float* __restrict__ pos_t, int* __restrict__ idx_out)
{
  const int tid = threadIdx.x;
  const int lane = tid & 63;
  const int p = blockIdx.x * 4 + (tid >> 6);
  const int b = p >> 11, i = p & (NN - 1);
  const float* px = pos_t + (size_t)b * 3 * NN;
  const float* py = px + NN;
  const float* pz = py + NN;
  const float xi = px[i], yi = py[i], zi = pz[i];
  const float sqi = xi * xi + yi * yi + zi * zi;
  float v[32];
#pragma unroll
  for (int t = 0; t < 32; ++t) {
    int j = t * 64 + lane;
    float xj = px[j], yj = py[j], zj = pz[j];
    float sqj = xj * xj + yj * yj + zj * zj;
    float dot = xi * xj + yi * yj + zi * zj;
    v[t] = sqi + sqj - 2.0f * dot;
  }
  for (int s = 0; s < KNN; ++s) {
    float bv = 3.4e38f; int bj = 1 << 30;
#pragma unroll
    for (int t = 0; t < 32; ++t) {
      if (v[t] < bv) { bv = v[t]; bj = t * 64 + lane; }
    }
#pragma unroll
    for (int m = 1; m < 64; m <<= 1) {
      float ov = __shfl_xor(bv, m);
      int   oj = __shfl_xor(bj, m);
      if (ov < bv || (ov == bv && oj < bj)) { bv = ov; bj = oj; }
    }
    if (lane == 0) idx_out[(size_t)p * KNN + s] = bj;
#pragma unroll
    for (int t = 0; t < 32; ++t)
      if (bj == t * 64 + lane) v[t] = 3.4e38f;
  }
}

// ---------------------------------------------------------------------------
// Pack weights into bf16 B-fragment layouts (frag f at [f*512 + lane*8 + j],
// value = W[k = ks*32 + q*8 + j][n]) + folded BN + biases + pos SoA transpose.
// ---------------------------------------------------------------------------
__global__ __launch_bounds__(256) void pack_weights(
    const float* __restrict__ attn_w1, const float* __restrict__ attn_w2,
    const float* __restrict__ pos_w2, const float* __restrict__ Wf,
    const float* __restrict__ w_out, const float* __restrict__ pos,
    const float* __restrict__ attn_b1, const float* __restrict__ abn_g,
    const float* __restrict__ abn_b, const float* __restrict__ abn_m,
    const float* __restrict__ abn_v,
    const float* __restrict__ pos_b1, const float* __restrict__ pbn_g,
    const float* __restrict__ pbn_b, const float* __restrict__ pbn_m,
    const float* __restrict__ pbn_v, const float* __restrict__ pos_b2,
    short* __restrict__ w1p, short* __restrict__ w2p, short* __restrict__ pw2p,
    short* __restrict__ wfp, short* __restrict__ wop,
    float* __restrict__ biasq,
    float* __restrict__ t1sc, float* __restrict__ t1bi,
    float* __restrict__ phsc, float* __restrict__ phbi,
    float* __restrict__ pos_t)
{
  int t = blockIdx.x * 256 + threadIdx.x;
  if (t < 65536) {                       // w1p: [128x512], 8 chunks of 64 cols
    int j = t & 7, lane = (t >> 3) & 63, ks = (t >> 9) & 3, nt = (t >> 11) & 3, ch = t >> 13;
    int q = lane >> 4, cc = lane & 15;
    int k = ks * 32 + q * 8 + j, n = ch * 64 + nt * 16 + cc;
    w1p[t] = f2bf(attn_w1[(size_t)k * AH + n]);
  } else if (t < 131072) {               // w2p: [512x128], 8 chunks of 64 rows
    int e = t - 65536;
    int j = e & 7, lane = (e >> 3) & 63, ks = (e >> 9) & 1, nt = (e >> 10) & 7, ch = e >> 13;
    int q = lane >> 4, cc = lane & 15;
    int k = ch * 64 + ks * 32 + q * 8 + j, n = nt * 16 + cc;
    w2p[e] = f2bf(attn_w2[(size_t)k * DIM + n]);
  } else if (t < 139264) {               // pw2p: pos_w2 [64x128]
    int e = t - 131072;
    int j = e & 7, lane = (e >> 3) & 63, ks = (e >> 9) & 1, nt = e >> 10;
    int q = lane >> 4, cc = lane & 15;
    int k = ks * 32 + q * 8 + j, n = nt * 16 + cc;
    pw2p[e] = f2bf(pos_w2[(size_t)k * DIM + n]);
  } else if (t < 188416) {               // wfp: Wf [128x384], 3 col-chunks
    int e = t - 139264;
    int j = e & 7, lane = (e >> 3) & 63, ks = (e >> 9) & 3, nt = (e >> 11) & 7, nc = e >> 14;
    int q = lane >> 4, cc = lane & 15;
    int k = ks * 32 + q * 8 + j, n = nc * 128 + nt * 16 + cc;
    wfp[e] = f2bf(Wf[(size_t)k * 384 + n]);
  } else if (t < 204800) {               // wop: w_out [128x128]
    int e = t - 188416;
    int j = e & 7, lane = (e >> 3) & 63, ks = (e >> 9) & 3, nt = (e >> 11) & 7;
    int q = lane >> 4, cc = lane & 15;
    int k = ks * 32 + q * 8 + j, n = nt * 16 + cc;
    wop[e] = f2bf(w_out[(size_t)k * DIM + n]);
  } else if (t < 205184) {               // biasq[384]: pos_b2 into q,v cols
    int c = t - 204800;
    biasq[c] = (c < 128) ? pos_b2[c] : ((c < 256) ? 0.0f : pos_b2[c - 256]);
  } else if (t < 205696) {
    int c = t - 205184;
    t1sc[c] = abn_g[c] * rsqrtf(abn_v[c] + EPS);
  } else if (t < 206208) {
    int c = t - 205696;
    float sc = abn_g[c] * rsqrtf(abn_v[c] + EPS);
    t1bi[c] = (attn_b1[c] - abn_m[c]) * sc + abn_b[c];
  } else if (t < 206272) {
    int c = t - 206208;
    phsc[c] = pbn_g[c] * rsqrtf(pbn_v[c] + EPS);
  } else if (t < 206336) {
    int c = t - 206272;
    float sc = pbn_g[c] * rsqrtf(pbn_v[c] + EPS);
    phbi[c] = (pos_b1[c] - pbn_m[c]) * sc + pbn_b[c];
  } else if (t < 206336 + NPTS * 3) {    // pos -> SoA pos_t[b][3][NN]
    int e = t - 206336;
    int p = e / 3, d = e - p * 3;
    int b = p >> 11, n = p & (NN - 1);
    pos_t[((size_t)b * 3 + d) * NN + n] = pos[e];
  }
}

// ---------------------------------------------------------------------------
// MFMA GEMM: qkv[16384x384] (bf16 out) = bf16(ori_x) @ wfp + biasq.
// M=64 blocks; 3 col-chunks looped inside (A staged once).
// ---------------------------------------------------------------------------
__global__ __launch_bounds__(256, 4) void gemm_in(
    const float* __restrict__ A, const short* __restrict__ wfp,
    const float* __restrict__ biasq, short* __restrict__ C)
{
  __shared__ short As[64 * 128];
  const int tid = threadIdx.x;
  const int lane = tid & 63, w = tid >> 6;
  const int wr = w >> 1, wc = w & 1;
  const int q = lane >> 4, cc = lane & 15;
  const int row0 = blockIdx.x * 64;
#pragma unroll
  for (int it = 0; it < 4; ++it) {
    int e = tid + it * 256;
    int row = e >> 4, cg = e & 15;
    const float* src = A + (size_t)(row0 + row) * 128 + cg * 8;
    float4 f0 = *(const float4*)src, f1 = *(const float4*)(src + 4);
    short8 v;
    v[0] = f2bf(f0.x); v[1] = f2bf(f0.y); v[2] = f2bf(f0.z); v[3] = f2bf(f0.w);
    v[4] = f2bf(f1.x); v[5] = f2bf(f1.y); v[6] = f2bf(f1.z); v[7] = f2bf(f1.w);
    *(short8*)(As + row * 128 + ((cg ^ (row & 15)) << 3)) = v;
  }
  __syncthreads();
  for (int nc = 0; nc < 3; ++nc) {
    floatx4 acc[2][4];
#pragma unroll
    for (int i = 0; i < 2; ++i)
#pragma unroll
      for (int jt = 0; jt < 4; ++jt) acc[i][jt] = (floatx4){0.f, 0.f, 0.f, 0.f};
#pragma unroll
    for (int ks = 0; ks < 4; ++ks) {
      short8 a8[2], b8[4];
#pragma unroll
      for (int i = 0; i < 2; ++i) {
        int row = (wr * 2 + i) * 16 + cc;
        a8[i] = *(const short8*)(As + row * 128 + (((ks * 4 + q) ^ cc) << 3));
      }
#pragma unroll
      for (int jt = 0; jt < 4; ++jt)
        b8[jt] = *(const short8*)(wfp + ((((nc * 8 + wc * 4 + jt) * 4 + ks) * 64 + lane) << 3));
#pragma unroll
      for (int i = 0; i < 2; ++i)
#pragma unroll
        for (int jt = 0; jt < 4; ++jt)
          acc[i][jt] = __builtin_amdgcn_mfma_f32_16x16x32_bf16(a8[i], b8[jt], acc[i][jt], 0, 0, 0);
    }
#pragma unroll
    for (int jt = 0; jt < 4; ++jt) {
      int colG = nc * 128 + (wc * 4 + jt) * 16 + cc;
      float bv = biasq[colG];
#pragma unroll
      for (int i = 0; i < 2; ++i)
#pragma unroll
        for (int r = 0; r < 4; ++r) {
          int row = (wr * 2 + i) * 16 + q * 4 + r;
          C[(size_t)(row0 + row) * 384 + colG] = f2bf(acc[i][jt][r] + bv);
        }
    }
  }
}

// ---------------------------------------------------------------------------
// MFMA GEMM: out[16384x128] = bf16(agg) @ wop + ori_x. M=64 blocks.
// ---------------------------------------------------------------------------
__global__ __launch_bounds__(256, 4) void gemm_out(
    const float* __restrict__ A, const short* __restrict__ wop,
    const float* __restrict__ R, float* __restrict__ C)
{
  __shared__ short As[64 * 128];
  const int tid = threadIdx.x;
  const int lane = tid & 63, w = tid >> 6;
  const int wr = w >> 1, wc = w & 1;
  const int q = lane >> 4, cc = lane & 15;
  const int row0 = blockIdx.x * 64;
#pragma unroll
  for (int it = 0; it < 4; ++it) {
    int e = tid + it * 256;
    int row = e >> 4, cg = e & 15;
    const float* src = A + (size_t)(row0 + row) * 128 + cg * 8;
    float4 f0 = *(const float4*)src, f1 = *(const float4*)(src + 4);
    short8 v;
    v[0] = f2bf(f0.x); v[1] = f2bf(f0.y); v[2] = f2bf(f0.z); v[3] = f2bf(f0.w);
    v[4] = f2bf(f1.x); v[5] = f2bf(f1.y); v[6] = f2bf(f1.z); v[7] = f2bf(f1.w);
    *(short8*)(As + row * 128 + ((cg ^ (row & 15)) << 3)) = v;
  }
  __syncthreads();
  floatx4 acc[2][4];
#pragma unroll
  for (int i = 0; i < 2; ++i)
#pragma unroll
    for (int jt = 0; jt < 4; ++jt) acc[i][jt] = (floatx4){0.f, 0.f, 0.f, 0.f};
#pragma unroll
  for (int ks = 0; ks < 4; ++ks) {
    short8 a8[2], b8[4];
#pragma unroll
    for (int i = 0; i < 2; ++i) {
      int row = (wr * 2 + i) * 16 + cc;
      a8[i] = *(const short8*)(As + row * 128 + (((ks * 4 + q) ^ cc) << 3));
    }
#pragma unroll
    for (int jt = 0; jt < 4; ++jt)
      b8[jt] = *(const short8*)(wop + ((((wc * 4 + jt) * 4 + ks) * 64 + lane) << 3));
#pragma unroll
    for (int i = 0; i < 2; ++i)
#pragma unroll
      for (int jt = 0; jt < 4; ++jt)
        acc[i][jt] = __builtin_amdgcn_mfma_f32_16x16x32_bf16(a8[i], b8[jt], acc[i][jt], 0, 0, 0);
  }
#pragma unroll
  for (int jt = 0; jt < 4; ++jt) {
    int col = (wc * 4 + jt) * 16 + cc;
#pragma unroll
    for (int i = 0; i < 2; ++i)
#pragma unroll
      for (int r = 0; r < 4; ++r) {
        int row = (wr * 2 + i) * 16 + q * 4 + r;
        size_t o = (size_t)(row0 + row) * 128 + col;
        C[o] = acc[i][jt][r] + R[o];
      }
  }
}

// ---------------------------------------------------------------------------
// Fused MFMA attention — ONE WAVE PER POINT, fully wave-local, ZERO barriers.
// Each wave owns its point's 16 neighbor rows x all columns end-to-end:
//   nbr/relp (lane<16) -> ph 16x64 in t1p[w] -> pe (16 MFMA) -> combine
//   a=q-k+pe into av_s[w-region] -> hoist af[4] -> park vpe in av_s ->
//   8 chunks { GEMM1 16 MFMA -> bn/relu -> t1p[w] -> GEMM2 16 MFMA } ->
//   softmax + aggregate.
// Same MFMA/VALU work per thread as round 4 (no redundancy; round 5's
// mistake was a 2x-redundant GEMM1 + tacc doubling -> spill). All LDS deps
// are within-wave (per-wave DS ops are in-order; compiler inserts lgkmcnt),
// so all 22 __syncthreads are gone. af halves to 4 frags (-16 VGPR).
// launch_bounds (256,3): the (256,4) 128-reg cap caused a 300MB scratch
// spill (rounds 1-2); cap ~170 fits cleanly.
// XCD-affinity: batch = blockIdx.x & 7.
// ---------------------------------------------------------------------------
__global__ __launch_bounds__(256, 3) void fused_attn(
    const float* __restrict__ pos, const short* __restrict__ qkv,
    const int* __restrict__ knn_idx,
    const float* __restrict__ pos_w1,
    const short* __restrict__ w1p, const short* __restrict__ w2p,
    const short* __restrict__ pw2p,
    const float* __restrict__ t1sc, const float* __restrict__ t1bi,
    const float* __restrict__ phsc, const float* __restrict__ phbi,
    const float* __restrict__ attn_b2,
    float* __restrict__ agg)
{
  __shared__ short av_s[64 * 128];      // 16 KB; wave w owns rows w*16..+16
  __shared__ short t1p[4][16 * 64];     // 8 KB; per-wave: ph, then t1 chunks
  __shared__ float relp_s[4][64];       // per-wave 16 x {x,y,z,pad}
  __shared__ int   nbr_s[4][16];

  const int tid = threadIdx.x;
  const int lane = tid & 63, w = tid >> 6;
  const int q = lane >> 4, cc = lane & 15;
  const int bb = blockIdx.x & 7;                     // XCD-affinity swizzle
  const int gp0 = bb * NN + (blockIdx.x >> 3) * 4;   // 4 points/block
  const int pt = gp0 + w;                            // this wave's point

  // wave-local staging: 16 neighbor idx + rel positions (lanes 0..15)
  if (lane < 16) {
    int nbr = knn_idx[(size_t)pt * KNN + lane];
    nbr_s[w][lane] = nbr;
    const float* pa = pos + (size_t)pt * 3;
    const float* pj = pos + ((size_t)bb * NN + nbr) * 3;
    relp_s[w][lane * 4 + 0] = pa[0] - pj[0];
    relp_s[w][lane * 4 + 1] = pa[1] - pj[1];
    relp_s[w][lane * 4 + 2] = pa[2] - pj[2];
  }
  // no barrier: consumers are this wave; per-wave DS ops are in-order

  short* t1w = t1p[w];

  // ph = relu(bn(relp @ pos_w1 + b1)) -> t1w (16 rows x 64 cols), col = lane
  {
    const int c = lane;
    float w1x = pos_w1[c], w1y = pos_w1[64 + c], w1z = pos_w1[128 + c];
    float sc = phsc[c], bi = phbi[c];
#pragma unroll
    for (int r = 0; r < 16; ++r) {
      float lin = relp_s[w][r * 4] * w1x + relp_s[w][r * 4 + 1] * w1y
                + relp_s[w][r * 4 + 2] * w1z;
      t1w[r * 64 + (((c >> 3) ^ (r & 7)) << 3) + (c & 7)] =
          f2bf(fmaxf(lin * sc + bi, 0.0f));
    }
  }

  // pe = ph @ pos_w2 : 16 rows x 128 cols (pos_b2 pre-folded into qkv q/v)
  floatx4 pe[8];
#pragma unroll
  for (int jt = 0; jt < 8; ++jt) pe[jt] = (floatx4){0.f, 0.f, 0.f, 0.f};
#pragma unroll
  for (int ks = 0; ks < 2; ++ks) {
    short8 a8 = *(const short8*)(t1w + cc * 64 + (((ks * 4 + q) ^ (cc & 7)) << 3));
#pragma unroll
    for (int jt = 0; jt < 8; ++jt) {
      short8 b8 = *(const short8*)(pw2p + (((jt * 2 + ks) * 64 + lane) << 3));
      pe[jt] = __builtin_amdgcn_mfma_f32_16x16x32_bf16(a8, b8, pe[jt], 0, 0, 0);
    }
  }

  // q values for this thread's columns (row = pt, col = jt*16+cc)
  float qreg[8];
#pragma unroll
  for (int jt = 0; jt < 8; ++jt)
    qreg[jt] = bf2f(qkv[(size_t)pt * 384 + jt * 16 + cc]);

  // combine: a = q - k_g + pe -> av_s (own rows); vpe = v_g + pe -> regs
  floatx4 vpe[8];
#pragma unroll
  for (int r = 0; r < 4; ++r) {
    int lr = q * 4 + r;                      // local row 0..15
    int row = w * 16 + lr;
    const short* kv = qkv + ((size_t)bb * NN + nbr_s[w][lr]) * 384;
    int sb = row * 128;
#pragma unroll
    for (int jt = 0; jt < 8; ++jt) {
      int col = jt * 16 + cc;
      float pev = pe[jt][r];
      av_s[sb + (((col >> 3) ^ lr) << 3) + (col & 7)] =
          f2bf(qreg[jt] - bf2f(kv[128 + col]) + pev);
      vpe[jt][r] = bf2f(kv[256 + col]) + pev;
    }
  }

  // hoist chunk-invariant A-fragments (own rows; in-order DS within wave)
  short8 af[4];
#pragma unroll
  for (int ks = 0; ks < 4; ++ks)
    af[ks] = *(const short8*)(av_s + (w * 16 + cc) * 128 + (((ks * 4 + q) ^ cc) << 3));

  // park vpe into av_s (thread-local slots; same thread reads them back)
#pragma unroll
  for (int r = 0; r < 4; ++r) {
    int lr = q * 4 + r;
    int sb = (w * 16 + lr) * 128;
#pragma unroll
    for (int jt = 0; jt < 8; ++jt) {
      int col = jt * 16 + cc;
      av_s[sb + (((col >> 3) ^ lr) << 3) + (col & 7)] = f2bf(vpe[jt][r]);
    }
  }

  floatx4 hacc[8];
#pragma unroll
  for (int jt = 0; jt < 8; ++jt) hacc[jt] = (floatx4){0.f, 0.f, 0.f, 0.f};

  for (int ch = 0; ch < 8; ++ch) {
    // GEMM1: t1 = a @ w1[:, ch*64:+64] for own 16 rows (A from registers)
    floatx4 tacc[4];
#pragma unroll
    for (int jt = 0; jt < 4; ++jt) tacc[jt] = (floatx4){0.f, 0.f, 0.f, 0.f};
#pragma unroll
    for (int ks = 0; ks < 4; ++ks) {
      short8 b8[4];
#pragma unroll
      for (int jt = 0; jt < 4; ++jt)
        b8[jt] = *(const short8*)(w1p + ((((ch * 4 + jt) * 4 + ks) * 64 + lane) << 3));
#pragma unroll
      for (int jt = 0; jt < 4; ++jt)
        tacc[jt] = __builtin_amdgcn_mfma_f32_16x16x32_bf16(af[ks], b8[jt], tacc[jt], 0, 0, 0);
    }
    // bn/relu -> t1w (WAR vs prev chunk's reads: per-wave DS in-order)
#pragma unroll
    for (int jt = 0; jt < 4; ++jt) {
      int colL = jt * 16 + cc;
      int colG = ch * 64 + colL;
      float sc = t1sc[colG], bi = t1bi[colG];
#pragma unroll
      for (int r = 0; r < 4; ++r) {
        int lr = q * 4 + r;
        t1w[lr * 64 + (((colL >> 3) ^ (lr & 7)) << 3) + (colL & 7)] =
            f2bf(fmaxf(tacc[jt][r] * sc + bi, 0.0f));
      }
    }
    // GEMM2: hacc += t1 @ w2[ch*64:+64, :]  (reads own tile; no barrier)
#pragma unroll
    for (int ks = 0; ks < 2; ++ks) {
      short8 a8 = *(const short8*)(t1w + cc * 64 + (((ks * 4 + q) ^ (cc & 7)) << 3));
#pragma unroll
      for (int jt = 0; jt < 8; ++jt) {
        short8 b8 = *(const short8*)(w2p + ((((ch * 8 + jt) * 2 + ks) * 64 + lane) << 3));
        hacc[jt] = __builtin_amdgcn_mfma_f32_16x16x32_bf16(a8, b8, hacc[jt], 0, 0, 0);
      }
    }
  }

  // softmax over the 16 neighbors per (point, channel) + aggregate
#pragma unroll
  for (int jt = 0; jt < 8; ++jt) {
    int col = jt * 16 + cc;
    float b2v = attn_b2[col];
    float v0[4], mx = -3.4e38f;
#pragma unroll
    for (int r = 0; r < 4; ++r) {
      v0[r] = (hacc[jt][r] + b2v) * SCALE;
      mx = fmaxf(mx, v0[r]);
    }
    mx = fmaxf(mx, __shfl_xor(mx, 16));
    mx = fmaxf(mx, __shfl_xor(mx, 32));
    float ex[4], sum = 0.f;
#pragma unroll
    for (int r = 0; r < 4; ++r) { ex[r] = __expf(v0[r] - mx); sum += ex[r]; }
    sum += __shfl_xor(sum, 16);
    sum += __shfl_xor(sum, 32);
    float inv = 1.0f / sum;
    float part = 0.f;
#pragma unroll
    for (int r = 0; r < 4; ++r) {
      int lr = q * 4 + r;
      int slot = (w * 16 + lr) * 128 + (((col >> 3) ^ lr) << 3) + (col & 7);
      part += ex[r] * bf2f(av_s[slot]);
    }
    part += __shfl_xor(part, 16);
    part += __shfl_xor(part, 32);
    if (q == 0) agg[(size_t)pt * DIM + col] = part * inv;
  }
}

extern "C" void kernel_launch(void* const* d_in, const int* in_sizes, int n_in,
                              void* d_out, int out_size, void* d_ws, size_t ws_size,
                              hipStream_t stream)
{
  const float* ori_x    = (const float*)d_in[0];
  const float* pos      = (const float*)d_in[1];
  const float* w_in     = (const float*)d_in[2];
  const float* w_qkv    = (const float*)d_in[3];
  const float* w_out    = (const float*)d_in[4];
  const float* pos_w1   = (const float*)d_in[5];
  const float* pos_b1   = (const float*)d_in[6];
  const float* pos_bn_g = (const float*)d_in[7];
  const float* pos_bn_b = (const float*)d_in[8];
  const float* pos_bn_m = (const float*)d_in[9];
  const float* pos_bn_v = (const float*)d_in[10];
  const float* pos_w2   = (const float*)d_in[11];
  const float* pos_b2   = (const float*)d_in[12];
  const float* attn_w1  = (const float*)d_in[13];
  const float* attn_b1  = (const float*)d_in[14];
  const float* attn_bn_g = (const float*)d_in[15];
  const float* attn_bn_b = (const float*)d_in[16];
  const float* attn_bn_m = (const float*)d_in[17];
  const float* attn_bn_v = (const float*)d_in[18];
  const float* attn_w2  = (const float*)d_in[19];
  const float* attn_b2  = (const float*)d_in[20];
  float* out = (float*)d_out;

  float* agg  = (float*)d_ws;                          // [NPTS*128] f32; Wf aliases head
  float* Wf   = agg;                                   // [128*384] (consumed by pack)
  short* qkvb = (short*)(agg + (size_t)NPTS * DIM);    // [NPTS*384] bf16
  int*   idx  = (int*)(qkvb + (size_t)NPTS * 3 * DIM); // [NPTS*16]
  short* w1p  = (short*)(idx + (size_t)NPTS * KNN);
  short* w2p  = w1p + 65536;
  short* pw2p = w2p + 65536;
  short* wfp  = pw2p + 8192;
  short* wop  = wfp + 49152;
  float* biasq = (float*)(wop + 16384);
  float* t1sc = biasq + 384;
  float* t1bi = t1sc + 512;
  float* phsc = t1bi + 512;
  float* phbi = phsc + 64;
  float* pos_t = phbi + 64;                            // [NB*3*NN]

  gemm_f32<<<dim3(2, 6), 256, 0, stream>>>(w_in, w_qkv, Wf, 128, 384, 128);
  pack_weights<<<998, 256, 0, stream>>>(attn_w1, attn_w2, pos_w2, Wf, w_out, pos,
      attn_b1, attn_bn_g, attn_bn_b, attn_bn_m, attn_bn_v,
      pos_b1, pos_bn_g, pos_bn_b, pos_bn_m, pos_bn_v, pos_b2,
      w1p, w2p, pw2p, wfp, wop, biasq, t1sc, t1bi, phsc, phbi, pos_t);
  gemm_in<<<NPTS / 64, 256, 0, stream>>>(ori_x, wfp, biasq, qkvb);
  knn_kernel<<<NPTS / 4, 256, 0, stream>>>(pos_t, idx);
  fused_attn<<<NPTS / 4, 256, 0, stream>>>(pos, qkvb, idx, pos_w1,
      w1p, w2p, pw2p, t1sc, t1bi, phsc, phbi, attn_b2, agg);
  gemm_out<<<NPTS / 64, 256, 0, stream>>>(agg, wop, ori_x, out);
}

// Round 7
// 345.416 us; speedup vs baseline: 1.4324x; 1.2053x over previous
//
#include <hip/hip_runtime.h>

#define EPS 1e-5f

constexpr int NB   = 8;
constexpr int NN   = 2048;
constexpr int DIM  = 128;
constexpr int KNN  = 16;
constexpr int AH   = 512;
constexpr int NPTS = NB * NN;
constexpr float SCALE = 0.08838834764831845f; // 1/sqrt(128)

typedef __attribute__((ext_vector_type(8))) short short8;
typedef __attribute__((ext_vector_type(4))) float floatx4;

// round-half-up bf16 conversion: 2 VALU ops (vs 5 for full RNE); threshold
// headroom is ~6x and ties are rare — measured absmax stays well under.
__device__ __forceinline__ short f2bf(float f) {
  union { float f; unsigned u; } a; a.f = f;
  return (short)((a.u + 0x8000u) >> 16);
}
__device__ __forceinline__ float bf2f(short s) {
  union { unsigned u; float f; } a; a.u = ((unsigned)(unsigned short)s) << 16;
  return a.f;
}

// ---------------------------------------------------------------------------
// fp32 tiled GEMM (only Wf = w_in @ w_qkv, tiny). 64x64 tile.
// ---------------------------------------------------------------------------
__global__ __launch_bounds__(256) void gemm_f32(
    const float* __restrict__ A, const float* __restrict__ W,
    float* __restrict__ C, int M, int N, int K)
{
  __shared__ float As[64][33];
  __shared__ float Ws[32][65];
  const int bm = blockIdx.x * 64, bn = blockIdx.y * 64;
  const int tid = threadIdx.x;
  const int tx = tid & 15, ty = tid >> 4;
  float acc[4][4] = {};
  for (int k0 = 0; k0 < K; k0 += 32) {
#pragma unroll
    for (int i = 0; i < 8; ++i) {
      int e = tid + i * 256;
      As[e >> 5][e & 31] = A[(size_t)(bm + (e >> 5)) * K + k0 + (e & 31)];
    }
#pragma unroll
    for (int i = 0; i < 8; ++i) {
      int e = tid + i * 256;
      Ws[e >> 6][e & 63] = W[(size_t)(k0 + (e >> 6)) * N + bn + (e & 63)];
    }
    __syncthreads();
#pragma unroll
    for (int kk = 0; kk < 32; ++kk) {
      float a[4], w[4];
#pragma unroll
      for (int i = 0; i < 4; ++i) a[i] = As[ty * 4 + i][kk];
#pragma unroll
      for (int j = 0; j < 4; ++j) w[j] = Ws[kk][tx * 4 + j];
#pragma unroll
      for (int i = 0; i < 4; ++i)
#pragma unroll
        for (int j = 0; j < 4; ++j)
          acc[i][j] += a[i] * w[j];
    }
    __syncthreads();
  }
#pragma unroll
  for (int i = 0; i < 4; ++i)
#pragma unroll
    for (int j = 0; j < 4; ++j)
      C[(size_t)(bm + ty * 4 + i) * N + bn + tx * 4 + j] = acc[i][j];
}

// ---------------------------------------------------------------------------
// KNN: one wave per point; 32 distances/lane in regs (SoA coalesced loads);
// 16 butterfly-argmin rounds; lowest-index tie-break. No LDS/barriers.
// ---------------------------------------------------------------------------
__global__ __launch_bounds__(256) void knn_kernel(
    const float* __restrict__ pos_t, int* __restrict__ idx_out)
{
  const int tid = threadIdx.x;
  const int lane = tid & 63;
  const int p = blockIdx.x * 4 + (tid >> 6);
  const int b = p >> 11, i = p & (NN - 1);
  const float* px = pos_t + (size_t)b * 3 * NN;
  const float* py = px + NN;
  const float* pz = py + NN;
  const float xi = px[i], yi = py[i], zi = pz[i];
  const float sqi = xi * xi + yi * yi + zi * zi;
  float v[32];
#pragma unroll
  for (int t = 0; t < 32; ++t) {
    int j = t * 64 + lane;
    float xj = px[j], yj = py[j], zj = pz[j];
    float sqj = xj * xj + yj * yj + zj * zj;
    float dot = xi * xj + yi * yj + zi * zj;
    v[t] = sqi + sqj - 2.0f * dot;
  }
  for (int s = 0; s < KNN; ++s) {
    float bv = 3.4e38f; int bj = 1 << 30;
#pragma unroll
    for (int t = 0; t < 32; ++t) {
      if (v[t] < bv) { bv = v[t]; bj = t * 64 + lane; }
    }
#pragma unroll
    for (int m = 1; m < 64; m <<= 1) {
      float ov = __shfl_xor(bv, m);
      int   oj = __shfl_xor(bj, m);
      if (ov < bv || (ov == bv && oj < bj)) { bv = ov; bj = oj; }
    }
    if (lane == 0) idx_out[(size_t)p * KNN + s] = bj;
#pragma unroll
    for (int t = 0; t < 32; ++t)
      if (bj == t * 64 + lane) v[t] = 3.4e38f;
  }
}

// ---------------------------------------------------------------------------
// Pack weights into bf16 B-fragment layouts (frag f at [f*512 + lane*8 + j],
// value = W[k = ks*32 + q*8 + j][n]) + folded BN + biases + pos SoA transpose.
// ---------------------------------------------------------------------------
__global__ __launch_bounds__(256) void pack_weights(
    const float* __restrict__ attn_w1, const float* __restrict__ attn_w2,
    const float* __restrict__ pos_w2, const float* __restrict__ Wf,
    const float* __restrict__ w_out, const float* __restrict__ pos,
    const float* __restrict__ attn_b1, const float* __restrict__ abn_g,
    const float* __restrict__ abn_b, const float* __restrict__ abn_m,
    const float* __restrict__ abn_v,
    const float* __restrict__ pos_b1, const float* __restrict__ pbn_g,
    const float* __restrict__ pbn_b, const float* __restrict__ pbn_m,
    const float* __restrict__ pbn_v, const float* __restrict__ pos_b2,
    short* __restrict__ w1p, short* __restrict__ w2p, short* __restrict__ pw2p,
    short* __restrict__ wfp, short* __restrict__ wop,
    float* __restrict__ biasq,
    float* __restrict__ t1sc, float* __restrict__ t1bi,
    float* __restrict__ phsc, float* __restrict__ phbi,
    float* __restrict__ pos_t)
{
  int t = blockIdx.x * 256 + threadIdx.x;
  if (t < 65536) {                       // w1p: [128x512], 8 chunks of 64 cols
    int j = t & 7, lane = (t >> 3) & 63, ks = (t >> 9) & 3, nt = (t >> 11) & 3, ch = t >> 13;
    int q = lane >> 4, cc = lane & 15;
    int k = ks * 32 + q * 8 + j, n = ch * 64 + nt * 16 + cc;
    w1p[t] = f2bf(attn_w1[(size_t)k * AH + n]);
  } else if (t < 131072) {               // w2p: [512x128], 8 chunks of 64 rows
    int e = t - 65536;
    int j = e & 7, lane = (e >> 3) & 63, ks = (e >> 9) & 1, nt = (e >> 10) & 7, ch = e >> 13;
    int q = lane >> 4, cc = lane & 15;
    int k = ch * 64 + ks * 32 + q * 8 + j, n = nt * 16 + cc;
    w2p[e] = f2bf(attn_w2[(size_t)k * DIM + n]);
  } else if (t < 139264) {               // pw2p: pos_w2 [64x128]
    int e = t - 131072;
    int j = e & 7, lane = (e >> 3) & 63, ks = (e >> 9) & 1, nt = e >> 10;
    int q = lane >> 4, cc = lane & 15;
    int k = ks * 32 + q * 8 + j, n = nt * 16 + cc;
    pw2p[e] = f2bf(pos_w2[(size_t)k * DIM + n]);
  } else if (t < 188416) {               // wfp: Wf [128x384], 3 col-chunks
    int e = t - 139264;
    int j = e & 7, lane = (e >> 3) & 63, ks = (e >> 9) & 3, nt = (e >> 11) & 7, nc = e >> 14;
    int q = lane >> 4, cc = lane & 15;
    int k = ks * 32 + q * 8 + j, n = nc * 128 + nt * 16 + cc;
    wfp[e] = f2bf(Wf[(size_t)k * 384 + n]);
  } else if (t < 204800) {               // wop: w_out [128x128]
    int e = t - 188416;
    int j = e & 7, lane = (e >> 3) & 63, ks = (e >> 9) & 3, nt = (e >> 11) & 7;
    int q = lane >> 4, cc = lane & 15;
    int k = ks * 32 + q * 8 + j, n = nt * 16 + cc;
    wop[e] = f2bf(w_out[(size_t)k * DIM + n]);
  } else if (t < 205184) {               // biasq[384]: pos_b2 into q,v cols
    int c = t - 204800;
    biasq[c] = (c < 128) ? pos_b2[c] : ((c < 256) ? 0.0f : pos_b2[c - 256]);
  } else if (t < 205696) {
    int c = t - 205184;
    t1sc[c] = abn_g[c] * rsqrtf(abn_v[c] + EPS);
  } else if (t < 206208) {
    int c = t - 205696;
    float sc = abn_g[c] * rsqrtf(abn_v[c] + EPS);
    t1bi[c] = (attn_b1[c] - abn_m[c]) * sc + abn_b[c];
  } else if (t < 206272) {
    int c = t - 206208;
    phsc[c] = pbn_g[c] * rsqrtf(pbn_v[c] + EPS);
  } else if (t < 206336) {
    int c = t - 206272;
    float sc = pbn_g[c] * rsqrtf(pbn_v[c] + EPS);
    phbi[c] = (pos_b1[c] - pbn_m[c]) * sc + pbn_b[c];
  } else if (t < 206336 + NPTS * 3) {    // pos -> SoA pos_t[b][3][NN]
    int e = t - 206336;
    int p = e / 3, d = e - p * 3;
    int b = p >> 11, n = p & (NN - 1);
    pos_t[((size_t)b * 3 + d) * NN + n] = pos[e];
  }
}

// ---------------------------------------------------------------------------
// MFMA GEMM: qkv[16384x384] (bf16 out) = bf16(ori_x) @ wfp + biasq.
// M=64 blocks; 3 col-chunks looped inside (A staged once).
// ---------------------------------------------------------------------------
__global__ __launch_bounds__(256, 4) void gemm_in(
    const float* __restrict__ A, const short* __restrict__ wfp,
    const float* __restrict__ biasq, short* __restrict__ C)
{
  __shared__ short As[64 * 128];
  const int tid = threadIdx.x;
  const int lane = tid & 63, w = tid >> 6;
  const int wr = w >> 1, wc = w & 1;
  const int q = lane >> 4, cc = lane & 15;
  const int row0 = blockIdx.x * 64;
#pragma unroll
  for (int it = 0; it < 4; ++it) {
    int e = tid + it * 256;
    int row = e >> 4, cg = e & 15;
    const float* src = A + (size_t)(row0 + row) * 128 + cg * 8;
    float4 f0 = *(const float4*)src, f1 = *(const float4*)(src + 4);
    short8 v;
    v[0] = f2bf(f0.x); v[1] = f2bf(f0.y); v[2] = f2bf(f0.z); v[3] = f2bf(f0.w);
    v[4] = f2bf(f1.x); v[5] = f2bf(f1.y); v[6] = f2bf(f1.z); v[7] = f2bf(f1.w);
    *(short8*)(As + row * 128 + ((cg ^ (row & 15)) << 3)) = v;
  }
  __syncthreads();
  for (int nc = 0; nc < 3; ++nc) {
    floatx4 acc[2][4];
#pragma unroll
    for (int i = 0; i < 2; ++i)
#pragma unroll
      for (int jt = 0; jt < 4; ++jt) acc[i][jt] = (floatx4){0.f, 0.f, 0.f, 0.f};
#pragma unroll
    for (int ks = 0; ks < 4; ++ks) {
      short8 a8[2], b8[4];
#pragma unroll
      for (int i = 0; i < 2; ++i) {
        int row = (wr * 2 + i) * 16 + cc;
        a8[i] = *(const short8*)(As + row * 128 + (((ks * 4 + q) ^ cc) << 3));
      }
#pragma unroll
      for (int jt = 0; jt < 4; ++jt)
        b8[jt] = *(const short8*)(wfp + ((((nc * 8 + wc * 4 + jt) * 4 + ks) * 64 + lane) << 3));
#pragma unroll
      for (int i = 0; i < 2; ++i)
#pragma unroll
        for (int jt = 0; jt < 4; ++jt)
          acc[i][jt] = __builtin_amdgcn_mfma_f32_16x16x32_bf16(a8[i], b8[jt], acc[i][jt], 0, 0, 0);
    }
#pragma unroll
    for (int jt = 0; jt < 4; ++jt) {
      int colG = nc * 128 + (wc * 4 + jt) * 16 + cc;
      float bv = biasq[colG];
#pragma unroll
      for (int i = 0; i < 2; ++i)
#pragma unroll
        for (int r = 0; r < 4; ++r) {
          int row = (wr * 2 + i) * 16 + q * 4 + r;
          C[(size_t)(row0 + row) * 384 + colG] = f2bf(acc[i][jt][r] + bv);
        }
    }
  }
}

// ---------------------------------------------------------------------------
// MFMA GEMM: out[16384x128] = bf16(agg) @ wop + ori_x. M=64 blocks.
// ---------------------------------------------------------------------------
__global__ __launch_bounds__(256, 4) void gemm_out(
    const float* __restrict__ A, const short* __restrict__ wop,
    const float* __restrict__ R, float* __restrict__ C)
{
  __shared__ short As[64 * 128];
  const int tid = threadIdx.x;
  const int lane = tid & 63, w = tid >> 6;
  const int wr = w >> 1, wc = w & 1;
  const int q = lane >> 4, cc = lane & 15;
  const int row0 = blockIdx.x * 64;
#pragma unroll
  for (int it = 0; it < 4; ++it) {
    int e = tid + it * 256;
    int row = e >> 4, cg = e & 15;
    const float* src = A + (size_t)(row0 + row) * 128 + cg * 8;
    float4 f0 = *(const float4*)src, f1 = *(const float4*)(src + 4);
    short8 v;
    v[0] = f2bf(f0.x); v[1] = f2bf(f0.y); v[2] = f2bf(f0.z); v[3] = f2bf(f0.w);
    v[4] = f2bf(f1.x); v[5] = f2bf(f1.y); v[6] = f2bf(f1.z); v[7] = f2bf(f1.w);
    *(short8*)(As + row * 128 + ((cg ^ (row & 15)) << 3)) = v;
  }
  __syncthreads();
  floatx4 acc[2][4];
#pragma unroll
  for (int i = 0; i < 2; ++i)
#pragma unroll
    for (int jt = 0; jt < 4; ++jt) acc[i][jt] = (floatx4){0.f, 0.f, 0.f, 0.f};
#pragma unroll
  for (int ks = 0; ks < 4; ++ks) {
    short8 a8[2], b8[4];
#pragma unroll
    for (int i = 0; i < 2; ++i) {
      int row = (wr * 2 + i) * 16 + cc;
      a8[i] = *(const short8*)(As + row * 128 + (((ks * 4 + q) ^ cc) << 3));
    }
#pragma unroll
    for (int jt = 0; jt < 4; ++jt)
      b8[jt] = *(const short8*)(wop + ((((wc * 4 + jt) * 4 + ks) * 64 + lane) << 3));
#pragma unroll
    for (int i = 0; i < 2; ++i)
#pragma unroll
      for (int jt = 0; jt < 4; ++jt)
        acc[i][jt] = __builtin_amdgcn_mfma_f32_16x16x32_bf16(a8[i], b8[jt], acc[i][jt], 0, 0, 0);
  }
#pragma unroll
  for (int jt = 0; jt < 4; ++jt) {
    int col = (wc * 4 + jt) * 16 + cc;
#pragma unroll
    for (int i = 0; i < 2; ++i)
#pragma unroll
      for (int r = 0; r < 4; ++r) {
        int row = (wr * 2 + i) * 16 + q * 4 + r;
        size_t o = (size_t)(row0 + row) * 128 + col;
        C[o] = acc[i][jt][r] + R[o];
      }
  }
}

// ---------------------------------------------------------------------------
// Fused MFMA attention: 4 points/block (M=64), 4 waves each 32 rows x 64-col
// wc-split (round-4 structure, best measured). Single-buffered t1, 2
// barriers/chunk, LDS 26.9 KB.
// THIS ROUND: accumulator-peak shave to cross the 128-unified-reg threshold
// (4 waves/SIMD instead of 3). Round 6 proved abs MFMA+VALU work is already
// minimal (30.8 + 59 us) and the rest is latency stall at 3 blocks/CU:
//   - GEMM1 computes its 2 col-tiles SEQUENTIALLY: tacc[2] (8 acc regs, was
//     16) + single b8 (4 regs, was 8). Same frags, same chain order.
//   - GEMM2 loads B in 2 batches of 2 (peak -8 regs vs batch-of-4).
// Arithmetic bitwise identical to round 4.
// launch_bounds (256,3): the (256,4) 128-reg cap caused a 300MB scratch
// spill (rounds 1-2); cap ~170 fits cleanly — if actual usage lands <=128
// the HW schedules 4 waves/SIMD on its own.
// XCD-affinity: batch = blockIdx.x & 7.
// ---------------------------------------------------------------------------
__global__ __launch_bounds__(256, 3) void fused_attn(
    const float* __restrict__ pos, const short* __restrict__ qkv,
    const int* __restrict__ knn_idx,
    const float* __restrict__ pos_w1,
    const short* __restrict__ w1p, const short* __restrict__ w2p,
    const short* __restrict__ pw2p,
    const float* __restrict__ t1sc, const float* __restrict__ t1bi,
    const float* __restrict__ phsc, const float* __restrict__ phbi,
    const float* __restrict__ attn_b2,
    float* __restrict__ agg)
{
  __shared__ short av_s[64 * 128];      // 16 KB, XOR swizzle on row&15 (a, then vpe)
  __shared__ short t1_s[64 * 64];       // 8 KB single buffer, XOR swizzle on row&7
  __shared__ short q_ss[4 * 128];       // 1 KB bf16 q rows
  __shared__ float relp_s[64 * 4];
  __shared__ int   nbr_s[64];

  const int tid = threadIdx.x;
  const int lane = tid & 63, w = tid >> 6;
  const int wr = w >> 1, wc = w & 1;
  const int q = lane >> 4, cc = lane & 15;
  const int bb = blockIdx.x & 7;                     // XCD-affinity swizzle
  const int gp0 = bb * NN + (blockIdx.x >> 3) * 4;   // 4 points/block

  if (tid < 64) nbr_s[tid] = knn_idx[(size_t)gp0 * KNN + tid];
  if (tid >= 64 && tid < 128) {  // stage q rows (bf16)
    int e = tid - 64;
    int p = e >> 4, seg = e & 15;
    *(short8*)(q_ss + p * 128 + seg * 8) =
        *(const short8*)(qkv + (size_t)(gp0 + p) * 384 + seg * 8);
  }
  __syncthreads();
  if (tid < 64) {
    int p = tid >> 4;
    int j = nbr_s[tid];
    const float* pa = pos + (size_t)(gp0 + p) * 3;
    const float* pj = pos + ((size_t)bb * NN + j) * 3;
    relp_s[tid * 4 + 0] = pa[0] - pj[0];
    relp_s[tid * 4 + 1] = pa[1] - pj[1];
    relp_s[tid * 4 + 2] = pa[2] - pj[2];
  }
  __syncthreads();

  // ph = relu(bn(relp @ pos_w1 + b1)) -> t1_s (64 rows x 64 cols)
#pragma unroll
  for (int r2 = 0; r2 < 16; ++r2) {
    int e = tid + r2 * 256;
    int row = e >> 6, c = e & 63;
    float lin = relp_s[row * 4] * pos_w1[c] + relp_s[row * 4 + 1] * pos_w1[64 + c]
              + relp_s[row * 4 + 2] * pos_w1[128 + c];
    t1_s[row * 64 + (((c >> 3) ^ (row & 7)) << 3) + (c & 7)] =
        f2bf(fmaxf(lin * phsc[c] + phbi[c], 0.0f));
  }
  __syncthreads();

  // pe = ph @ pos_w2 (pos_b2 pre-folded into qkv q/v cols)
  floatx4 pe[2][4];
#pragma unroll
  for (int i = 0; i < 2; ++i)
#pragma unroll
    for (int jt = 0; jt < 4; ++jt) pe[i][jt] = (floatx4){0.f, 0.f, 0.f, 0.f};
#pragma unroll
  for (int ks = 0; ks < 2; ++ks) {
    short8 a8[2];
#pragma unroll
    for (int i = 0; i < 2; ++i) {
      int row = (wr * 2 + i) * 16 + cc;
      a8[i] = *(const short8*)(t1_s + row * 64 + (((ks * 4 + q) ^ (row & 7)) << 3));
    }
#pragma unroll
    for (int jt = 0; jt < 4; ++jt) {
      short8 b8 = *(const short8*)(pw2p + ((((wc * 4 + jt) * 2 + ks) * 64 + lane) << 3));
#pragma unroll
      for (int i = 0; i < 2; ++i)
        pe[i][jt] = __builtin_amdgcn_mfma_f32_16x16x32_bf16(a8[i], b8, pe[i][jt], 0, 0, 0);
    }
  }

  // preload q values for this thread's (row-tile, col) positions
  float qreg[2][4];
#pragma unroll
  for (int i = 0; i < 2; ++i)
#pragma unroll
    for (int jt = 0; jt < 4; ++jt)
      qreg[i][jt] = bf2f(q_ss[(wr * 2 + i) * 128 + (wc * 4 + jt) * 16 + cc]);

  // combine: a = q - k_g + pe -> av_s ; vpe = v_g + pe -> short-lived regs.
  // Loop order (i, r, jt): neighbor base pointer computed once per row.
  floatx4 vpe[2][4];
#pragma unroll
  for (int i = 0; i < 2; ++i) {
    int rt = wr * 2 + i;
#pragma unroll
    for (int r = 0; r < 4; ++r) {
      int row = rt * 16 + q * 4 + r;
      const short* kv = qkv + ((size_t)bb * NN + nbr_s[row]) * 384;
      int sb = row * 128, sx = row & 15;
#pragma unroll
      for (int jt = 0; jt < 4; ++jt) {
        int col = (wc * 4 + jt) * 16 + cc;
        float pev = pe[i][jt][r];
        av_s[sb + (((col >> 3) ^ sx) << 3) + (col & 7)] =
            f2bf(qreg[i][jt] - bf2f(kv[128 + col]) + pev);
        vpe[i][jt][r] = bf2f(kv[256 + col]) + pev;
      }
    }
  }
  __syncthreads();   // av_s (=a) fully built; pe reads of t1_s complete

  // Hoist chunk-invariant A-fragments into registers (used every chunk).
  short8 af[2][4];
#pragma unroll
  for (int i = 0; i < 2; ++i) {
    int row = (wr * 2 + i) * 16 + cc;
#pragma unroll
    for (int ks = 0; ks < 4; ++ks)
      af[i][ks] = *(const short8*)(av_s + row * 128 + (((ks * 4 + q) ^ cc) << 3));
  }
  __syncthreads();   // all a-frags consumed; av_s reusable

  // Park vpe into av_s (thread-local slots; same thread reads them back).
#pragma unroll
  for (int i = 0; i < 2; ++i) {
    int rt = wr * 2 + i;
#pragma unroll
    for (int r = 0; r < 4; ++r) {
      int row = rt * 16 + q * 4 + r;
      int sb = row * 128, sx = row & 15;
#pragma unroll
      for (int jt = 0; jt < 4; ++jt) {
        int col = (wc * 4 + jt) * 16 + cc;
        av_s[sb + (((col >> 3) ^ sx) << 3) + (col & 7)] = f2bf(vpe[i][jt][r]);
      }
    }
  }

  floatx4 hacc[2][4];
#pragma unroll
  for (int i = 0; i < 2; ++i)
#pragma unroll
    for (int jt = 0; jt < 4; ++jt) hacc[i][jt] = (floatx4){0.f, 0.f, 0.f, 0.f};

  for (int ch = 0; ch < 8; ++ch) {
    // GEMM1 per col-tile: tacc[2] (8 acc regs, was 16) + single b8.
#pragma unroll
    for (int jt = 0; jt < 2; ++jt) {
      floatx4 tacc[2];
      tacc[0] = (floatx4){0.f, 0.f, 0.f, 0.f};
      tacc[1] = (floatx4){0.f, 0.f, 0.f, 0.f};
#pragma unroll
      for (int ks = 0; ks < 4; ++ks) {
        short8 b8 = *(const short8*)(w1p + ((((ch * 4 + wc * 2 + jt) * 4 + ks) * 64 + lane) << 3));
#pragma unroll
        for (int i = 0; i < 2; ++i)
          tacc[i] = __builtin_amdgcn_mfma_f32_16x16x32_bf16(af[i][ks], b8, tacc[i], 0, 0, 0);
      }
      // bn/relu -> t1_s (this col-tile, swizzled)
      int colL = (wc * 2 + jt) * 16 + cc;
      int colG = ch * 64 + colL;
      float sc = t1sc[colG], bi = t1bi[colG];
#pragma unroll
      for (int i = 0; i < 2; ++i)
#pragma unroll
        for (int r = 0; r < 4; ++r) {
          int row = (wr * 2 + i) * 16 + q * 4 + r;
          t1_s[row * 64 + (((colL >> 3) ^ (row & 7)) << 3) + (colL & 7)] =
              f2bf(fmaxf(tacc[i][r] * sc + bi, 0.0f));
        }
    }
    __syncthreads();   // t1 visible to all waves
    // GEMM2: hacc += t1 @ w2[ch*64 : +64, :]; B in 2 batches of 2.
#pragma unroll
    for (int ks = 0; ks < 2; ++ks) {
      short8 a8[2];
#pragma unroll
      for (int i = 0; i < 2; ++i) {
        int row = (wr * 2 + i) * 16 + cc;
        a8[i] = *(const short8*)(t1_s + row * 64 + (((ks * 4 + q) ^ (row & 7)) << 3));
      }
#pragma unroll
      for (int jh = 0; jh < 2; ++jh) {
        short8 b8[2];
#pragma unroll
        for (int j2 = 0; j2 < 2; ++j2)
          b8[j2] = *(const short8*)(w2p + ((((ch * 8 + wc * 4 + jh * 2 + j2) * 2 + ks) * 64 + lane) << 3));
#pragma unroll
        for (int i = 0; i < 2; ++i)
#pragma unroll
          for (int j2 = 0; j2 < 2; ++j2)
            hacc[i][jh * 2 + j2] = __builtin_amdgcn_mfma_f32_16x16x32_bf16(a8[i], b8[j2], hacc[i][jh * 2 + j2], 0, 0, 0);
      }
    }
    __syncthreads();   // all t1 reads done before next chunk overwrites
  }

  // softmax over the 16 neighbors per (point, channel) + aggregate
#pragma unroll
  for (int i = 0; i < 2; ++i) {
    int rt = wr * 2 + i;
#pragma unroll
    for (int jt = 0; jt < 4; ++jt) {
      int col = (wc * 4 + jt) * 16 + cc;
      float b2v = attn_b2[col];
      float v0[4], mx = -3.4e38f;
#pragma unroll
      for (int r = 0; r < 4; ++r) {
        v0[r] = (hacc[i][jt][r] + b2v) * SCALE;
        mx = fmaxf(mx, v0[r]);
      }
      mx = fmaxf(mx, __shfl_xor(mx, 16));
      mx = fmaxf(mx, __shfl_xor(mx, 32));
      float ex[4], sum = 0.f;
#pragma unroll
      for (int r = 0; r < 4; ++r) { ex[r] = __expf(v0[r] - mx); sum += ex[r]; }
      sum += __shfl_xor(sum, 16);
      sum += __shfl_xor(sum, 32);
      float inv = 1.0f / sum;
      float part = 0.f;
#pragma unroll
      for (int r = 0; r < 4; ++r) {
        int row = rt * 16 + q * 4 + r;
        int slot = row * 128 + (((col >> 3) ^ (row & 15)) << 3) + (col & 7);
        part += ex[r] * bf2f(av_s[slot]);
      }
      part += __shfl_xor(part, 16);
      part += __shfl_xor(part, 32);
      if (q == 0) agg[(size_t)(gp0 + rt) * DIM + col] = part * inv;
    }
  }
}

extern "C" void kernel_launch(void* const* d_in, const int* in_sizes, int n_in,
                              void* d_out, int out_size, void* d_ws, size_t ws_size,
                              hipStream_t stream)
{
  const float* ori_x    = (const float*)d_in[0];
  const float* pos      = (const float*)d_in[1];
  const float* w_in     = (const float*)d_in[2];
  const float* w_qkv    = (const float*)d_in[3];
  const float* w_out    = (const float*)d_in[4];
  const float* pos_w1   = (const float*)d_in[5];
  const float* pos_b1   = (const float*)d_in[6];
  const float* pos_bn_g = (const float*)d_in[7];
  const float* pos_bn_b = (const float*)d_in[8];
  const float* pos_bn_m = (const float*)d_in[9];
  const float* pos_bn_v = (const float*)d_in[10];
  const float* pos_w2   = (const float*)d_in[11];
  const float* pos_b2   = (const float*)d_in[12];
  const float* attn_w1  = (const float*)d_in[13];
  const float* attn_b1  = (const float*)d_in[14];
  const float* attn_bn_g = (const float*)d_in[15];
  const float* attn_bn_b = (const float*)d_in[16];
  const float* attn_bn_m = (const float*)d_in[17];
  const float* attn_bn_v = (const float*)d_in[18];
  const float* attn_w2  = (const float*)d_in[19];
  const float* attn_b2  = (const float*)d_in[20];
  float* out = (float*)d_out;

  float* agg  = (float*)d_ws;                          // [NPTS*128] f32; Wf aliases head
  float* Wf   = agg;                                   // [128*384] (consumed by pack)
  short* qkvb = (short*)(agg + (size_t)NPTS * DIM);    // [NPTS*384] bf16
  int*   idx  = (int*)(qkvb + (size_t)NPTS * 3 * DIM); // [NPTS*16]
  short* w1p  = (short*)(idx + (size_t)NPTS * KNN);
  short* w2p  = w1p + 65536;
  short* pw2p = w2p + 65536;
  short* wfp  = pw2p + 8192;
  short* wop  = wfp + 49152;
  float* biasq = (float*)(wop + 16384);
  float* t1sc = biasq + 384;
  float* t1bi = t1sc + 512;
  float* phsc = t1bi + 512;
  float* phbi = phsc + 64;
  float* pos_t = phbi + 64;                            // [NB*3*NN]

  gemm_f32<<<dim3(2, 6), 256, 0, stream>>>(w_in, w_qkv, Wf, 128, 384, 128);
  pack_weights<<<998, 256, 0, stream>>>(attn_w1, attn_w2, pos_w2, Wf, w_out, pos,
      attn_b1, attn_bn_g, attn_bn_b, attn_bn_m, attn_bn_v,
      pos_b1, pos_bn_g, pos_bn_b, pos_bn_m, pos_bn_v, pos_b2,
      w1p, w2p, pw2p, wfp, wop, biasq, t1sc, t1bi, phsc, phbi, pos_t);
  gemm_in<<<NPTS / 64, 256, 0, stream>>>(ori_x, wfp, biasq, qkvb);
  knn_kernel<<<NPTS / 4, 256, 0, stream>>>(pos_t, idx);
  fused_attn<<<NPTS / 4, 256, 0, stream>>>(pos, qkvb, idx, pos_w1,
      w1p, w2p, pw2p, t1sc, t1bi, phsc, phbi, attn_b2, agg);
  gemm_out<<<NPTS / 64, 256, 0, stream>>>(agg, wop, ori_x, out);
}

// Round 8
// 344.778 us; speedup vs baseline: 1.4350x; 1.0019x over previous
//
#include <hip/hip_runtime.h>

#define EPS 1e-5f

constexpr int NB   = 8;
constexpr int NN   = 2048;
constexpr int DIM  = 128;
constexpr int KNN  = 16;
constexpr int AH   = 512;
constexpr int NPTS = NB * NN;
constexpr float SCALE = 0.08838834764831845f; // 1/sqrt(128)

typedef __attribute__((ext_vector_type(8))) short short8;
typedef __attribute__((ext_vector_type(4))) float floatx4;

// round-half-up bf16 conversion: 2 VALU ops (vs 5 for full RNE); threshold
// headroom is ~6x and ties are rare — measured absmax stays well under.
__device__ __forceinline__ short f2bf(float f) {
  union { float f; unsigned u; } a; a.f = f;
  return (short)((a.u + 0x8000u) >> 16);
}
__device__ __forceinline__ float bf2f(short s) {
  union { unsigned u; float f; } a; a.u = ((unsigned)(unsigned short)s) << 16;
  return a.f;
}

// ---------------------------------------------------------------------------
// fp32 tiled GEMM (only Wf = w_in @ w_qkv, tiny). 64x64 tile.
// ---------------------------------------------------------------------------
__global__ __launch_bounds__(256) void gemm_f32(
    const float* __restrict__ A, const float* __restrict__ W,
    float* __restrict__ C, int M, int N, int K)
{
  __shared__ float As[64][33];
  __shared__ float Ws[32][65];
  const int bm = blockIdx.x * 64, bn = blockIdx.y * 64;
  const int tid = threadIdx.x;
  const int tx = tid & 15, ty = tid >> 4;
  float acc[4][4] = {};
  for (int k0 = 0; k0 < K; k0 += 32) {
#pragma unroll
    for (int i = 0; i < 8; ++i) {
      int e = tid + i * 256;
      As[e >> 5][e & 31] = A[(size_t)(bm + (e >> 5)) * K + k0 + (e & 31)];
    }
#pragma unroll
    for (int i = 0; i < 8; ++i) {
      int e = tid + i * 256;
      Ws[e >> 6][e & 63] = W[(size_t)(k0 + (e >> 6)) * N + bn + (e & 63)];
    }
    __syncthreads();
#pragma unroll
    for (int kk = 0; kk < 32; ++kk) {
      float a[4], w[4];
#pragma unroll
      for (int i = 0; i < 4; ++i) a[i] = As[ty * 4 + i][kk];
#pragma unroll
      for (int j = 0; j < 4; ++j) w[j] = Ws[kk][tx * 4 + j];
#pragma unroll
      for (int i = 0; i < 4; ++i)
#pragma unroll
        for (int j = 0; j < 4; ++j)
          acc[i][j] += a[i] * w[j];
    }
    __syncthreads();
  }
#pragma unroll
  for (int i = 0; i < 4; ++i)
#pragma unroll
    for (int j = 0; j < 4; ++j)
      C[(size_t)(bm + ty * 4 + i) * N + bn + tx * 4 + j] = acc[i][j];
}

// ---------------------------------------------------------------------------
// Pack weights into bf16 B-fragment layouts (frag f at [f*512 + lane*8 + j],
// value = W[k = ks*32 + q*8 + j][n]) + folded BN + biases + pos SoA transpose.
// ---------------------------------------------------------------------------
__global__ __launch_bounds__(256) void pack_weights(
    const float* __restrict__ attn_w1, const float* __restrict__ attn_w2,
    const float* __restrict__ pos_w2, const float* __restrict__ Wf,
    const float* __restrict__ w_out, const float* __restrict__ pos,
    const float* __restrict__ attn_b1, const float* __restrict__ abn_g,
    const float* __restrict__ abn_b, const float* __restrict__ abn_m,
    const float* __restrict__ abn_v,
    const float* __restrict__ pos_b1, const float* __restrict__ pbn_g,
    const float* __restrict__ pbn_b, const float* __restrict__ pbn_m,
    const float* __restrict__ pbn_v, const float* __restrict__ pos_b2,
    short* __restrict__ w1p, short* __restrict__ w2p, short* __restrict__ pw2p,
    short* __restrict__ wfp, short* __restrict__ wop,
    float* __restrict__ biasq,
    float* __restrict__ t1sc, float* __restrict__ t1bi,
    float* __restrict__ phsc, float* __restrict__ phbi,
    float* __restrict__ pos_t)
{
  int t = blockIdx.x * 256 + threadIdx.x;
  if (t < 65536) {                       // w1p: [128x512], 8 chunks of 64 cols
    int j = t & 7, lane = (t >> 3) & 63, ks = (t >> 9) & 3, nt = (t >> 11) & 3, ch = t >> 13;
    int q = lane >> 4, cc = lane & 15;
    int k = ks * 32 + q * 8 + j, n = ch * 64 + nt * 16 + cc;
    w1p[t] = f2bf(attn_w1[(size_t)k * AH + n]);
  } else if (t < 131072) {               // w2p: [512x128], 8 chunks of 64 rows
    int e = t - 65536;
    int j = e & 7, lane = (e >> 3) & 63, ks = (e >> 9) & 1, nt = (e >> 10) & 7, ch = e >> 13;
    int q = lane >> 4, cc = lane & 15;
    int k = ch * 64 + ks * 32 + q * 8 + j, n = nt * 16 + cc;
    w2p[e] = f2bf(attn_w2[(size_t)k * DIM + n]);
  } else if (t < 139264) {               // pw2p: pos_w2 [64x128]
    int e = t - 131072;
    int j = e & 7, lane = (e >> 3) & 63, ks = (e >> 9) & 1, nt = e >> 10;
    int q = lane >> 4, cc = lane & 15;
    int k = ks * 32 + q * 8 + j, n = nt * 16 + cc;
    pw2p[e] = f2bf(pos_w2[(size_t)k * DIM + n]);
  } else if (t < 188416) {               // wfp: Wf [128x384], 3 col-chunks
    int e = t - 139264;
    int j = e & 7, lane = (e >> 3) & 63, ks = (e >> 9) & 3, nt = (e >> 11) & 7, nc = e >> 14;
    int q = lane >> 4, cc = lane & 15;
    int k = ks * 32 + q * 8 + j, n = nc * 128 + nt * 16 + cc;
    wfp[e] = f2bf(Wf[(size_t)k * 384 + n]);
  } else if (t < 204800) {               // wop: w_out [128x128]
    int e = t - 188416;
    int j = e & 7, lane = (e >> 3) & 63, ks = (e >> 9) & 3, nt = (e >> 11) & 7;
    int q = lane >> 4, cc = lane & 15;
    int k = ks * 32 + q * 8 + j, n = nt * 16 + cc;
    wop[e] = f2bf(w_out[(size_t)k * DIM + n]);
  } else if (t < 205184) {               // biasq[384]: pos_b2 into q,v cols
    int c = t - 204800;
    biasq[c] = (c < 128) ? pos_b2[c] : ((c < 256) ? 0.0f : pos_b2[c - 256]);
  } else if (t < 205696) {
    int c = t - 205184;
    t1sc[c] = abn_g[c] * rsqrtf(abn_v[c] + EPS);
  } else if (t < 206208) {
    int c = t - 205696;
    float sc = abn_g[c] * rsqrtf(abn_v[c] + EPS);
    t1bi[c] = (attn_b1[c] - abn_m[c]) * sc + abn_b[c];
  } else if (t < 206272) {
    int c = t - 206208;
    phsc[c] = pbn_g[c] * rsqrtf(pbn_v[c] + EPS);
  } else if (t < 206336) {
    int c = t - 206272;
    float sc = pbn_g[c] * rsqrtf(pbn_v[c] + EPS);
    phbi[c] = (pos_b1[c] - pbn_m[c]) * sc + pbn_b[c];
  } else if (t < 206336 + NPTS * 3) {    // pos -> SoA pos_t[b][3][NN]
    int e = t - 206336;
    int p = e / 3, d = e - p * 3;
    int b = p >> 11, n = p & (NN - 1);
    pos_t[((size_t)b * 3 + d) * NN + n] = pos[e];
  }
}

// ---------------------------------------------------------------------------
// MFMA GEMM: qkv[16384x384] (bf16 out) = bf16(ori_x) @ wfp + biasq.
// Grid (256, 3): blockIdx.y = col-chunk (was an inner loop at 1 block/CU —
// latency-bound; 768 blocks = 3/CU). A-tile staged per block (3x redundant
// reads of ori_x = 24 MB via L2/L3, trivial).
// ---------------------------------------------------------------------------
__global__ __launch_bounds__(256, 4) void gemm_in(
    const float* __restrict__ A, const short* __restrict__ wfp,
    const float* __restrict__ biasq, short* __restrict__ C)
{
  __shared__ short As[64 * 128];
  const int tid = threadIdx.x;
  const int lane = tid & 63, w = tid >> 6;
  const int wr = w >> 1, wc = w & 1;
  const int q = lane >> 4, cc = lane & 15;
  const int row0 = blockIdx.x * 64;
  const int nc = blockIdx.y;
#pragma unroll
  for (int it = 0; it < 4; ++it) {
    int e = tid + it * 256;
    int row = e >> 4, cg = e & 15;
    const float* src = A + (size_t)(row0 + row) * 128 + cg * 8;
    float4 f0 = *(const float4*)src, f1 = *(const float4*)(src + 4);
    short8 v;
    v[0] = f2bf(f0.x); v[1] = f2bf(f0.y); v[2] = f2bf(f0.z); v[3] = f2bf(f0.w);
    v[4] = f2bf(f1.x); v[5] = f2bf(f1.y); v[6] = f2bf(f1.z); v[7] = f2bf(f1.w);
    *(short8*)(As + row * 128 + ((cg ^ (row & 15)) << 3)) = v;
  }
  __syncthreads();
  floatx4 acc[2][4];
#pragma unroll
  for (int i = 0; i < 2; ++i)
#pragma unroll
    for (int jt = 0; jt < 4; ++jt) acc[i][jt] = (floatx4){0.f, 0.f, 0.f, 0.f};
#pragma unroll
  for (int ks = 0; ks < 4; ++ks) {
    short8 a8[2], b8[4];
#pragma unroll
    for (int i = 0; i < 2; ++i) {
      int row = (wr * 2 + i) * 16 + cc;
      a8[i] = *(const short8*)(As + row * 128 + (((ks * 4 + q) ^ cc) << 3));
    }
#pragma unroll
    for (int jt = 0; jt < 4; ++jt)
      b8[jt] = *(const short8*)(wfp + ((((nc * 8 + wc * 4 + jt) * 4 + ks) * 64 + lane) << 3));
#pragma unroll
    for (int i = 0; i < 2; ++i)
#pragma unroll
      for (int jt = 0; jt < 4; ++jt)
        acc[i][jt] = __builtin_amdgcn_mfma_f32_16x16x32_bf16(a8[i], b8[jt], acc[i][jt], 0, 0, 0);
  }
#pragma unroll
  for (int jt = 0; jt < 4; ++jt) {
    int colG = nc * 128 + (wc * 4 + jt) * 16 + cc;
    float bv = biasq[colG];
#pragma unroll
    for (int i = 0; i < 2; ++i)
#pragma unroll
      for (int r = 0; r < 4; ++r) {
        int row = (wr * 2 + i) * 16 + q * 4 + r;
        C[(size_t)(row0 + row) * 384 + colG] = f2bf(acc[i][jt][r] + bv);
      }
  }
}

// ---------------------------------------------------------------------------
// MFMA GEMM: out[16384x128] = bf16(agg) @ wop + ori_x. M=64 blocks.
// ---------------------------------------------------------------------------
__global__ __launch_bounds__(256, 4) void gemm_out(
    const float* __restrict__ A, const short* __restrict__ wop,
    const float* __restrict__ R, float* __restrict__ C)
{
  __shared__ short As[64 * 128];
  const int tid = threadIdx.x;
  const int lane = tid & 63, w = tid >> 6;
  const int wr = w >> 1, wc = w & 1;
  const int q = lane >> 4, cc = lane & 15;
  const int row0 = blockIdx.x * 64;
#pragma unroll
  for (int it = 0; it < 4; ++it) {
    int e = tid + it * 256;
    int row = e >> 4, cg = e & 15;
    const float* src = A + (size_t)(row0 + row) * 128 + cg * 8;
    float4 f0 = *(const float4*)src, f1 = *(const float4*)(src + 4);
    short8 v;
    v[0] = f2bf(f0.x); v[1] = f2bf(f0.y); v[2] = f2bf(f0.z); v[3] = f2bf(f0.w);
    v[4] = f2bf(f1.x); v[5] = f2bf(f1.y); v[6] = f2bf(f1.z); v[7] = f2bf(f1.w);
    *(short8*)(As + row * 128 + ((cg ^ (row & 15)) << 3)) = v;
  }
  __syncthreads();
  floatx4 acc[2][4];
#pragma unroll
  for (int i = 0; i < 2; ++i)
#pragma unroll
    for (int jt = 0; jt < 4; ++jt) acc[i][jt] = (floatx4){0.f, 0.f, 0.f, 0.f};
#pragma unroll
  for (int ks = 0; ks < 4; ++ks) {
    short8 a8[2], b8[4];
#pragma unroll
    for (int i = 0; i < 2; ++i) {
      int row = (wr * 2 + i) * 16 + cc;
      a8[i] = *(const short8*)(As + row * 128 + (((ks * 4 + q) ^ cc) << 3));
    }
#pragma unroll
    for (int jt = 0; jt < 4; ++jt)
      b8[jt] = *(const short8*)(wop + ((((wc * 4 + jt) * 4 + ks) * 64 + lane) << 3));
#pragma unroll
    for (int i = 0; i < 2; ++i)
#pragma unroll
      for (int jt = 0; jt < 4; ++jt)
        acc[i][jt] = __builtin_amdgcn_mfma_f32_16x16x32_bf16(a8[i], b8[jt], acc[i][jt], 0, 0, 0);
  }
#pragma unroll
  for (int jt = 0; jt < 4; ++jt) {
    int col = (wc * 4 + jt) * 16 + cc;
#pragma unroll
    for (int i = 0; i < 2; ++i)
#pragma unroll
      for (int r = 0; r < 4; ++r) {
        int row = (wr * 2 + i) * 16 + q * 4 + r;
        size_t o = (size_t)(row0 + row) * 128 + col;
        C[o] = acc[i][jt][r] + R[o];
      }
  }
}

// ---------------------------------------------------------------------------
// Fused KNN + MFMA attention: 4 points/block, 4 waves (round-7 tile split).
// NEW: each wave computes its OWN point's KNN in-kernel (identical scan +
// butterfly-argmin + tie-break as the old knn_kernel -> identical neighbor
// set), writing nbr/relp straight to LDS. The ~45us standalone VALU-only knn
// kernel disappears; its work packs into fused_attn's ~36% idle-issue stall.
// Also deletes the idx global round-trip and one launch.
// Main loop = round-7: single-buffered t1, 2 barriers/chunk, seq GEMM1
// col-tiles (8-reg tacc), GEMM2 B in 2x2 batches. launch_bounds (256,3):
// the (256,4) cap spilled 300MB (rounds 1-2).
// XCD-affinity: batch = blockIdx.x & 7.
// ---------------------------------------------------------------------------
__global__ __launch_bounds__(256, 3) void fused_attn(
    const float* __restrict__ pos_t, const short* __restrict__ qkv,
    const float* __restrict__ pos_w1,
    const short* __restrict__ w1p, const short* __restrict__ w2p,
    const short* __restrict__ pw2p,
    const float* __restrict__ t1sc, const float* __restrict__ t1bi,
    const float* __restrict__ phsc, const float* __restrict__ phbi,
    const float* __restrict__ attn_b2,
    float* __restrict__ agg)
{
  __shared__ short av_s[64 * 128];      // 16 KB, XOR swizzle on row&15 (a, then vpe)
  __shared__ short t1_s[64 * 64];       // 8 KB single buffer, XOR swizzle on row&7
  __shared__ short q_ss[4 * 128];       // 1 KB bf16 q rows
  __shared__ float relp_s[64 * 4];
  __shared__ int   nbr_s[64];

  const int tid = threadIdx.x;
  const int lane = tid & 63, w = tid >> 6;
  const int wr = w >> 1, wc = w & 1;
  const int q = lane >> 4, cc = lane & 15;
  const int bb = blockIdx.x & 7;                     // XCD-affinity swizzle
  const int ip0 = (blockIdx.x >> 3) * 4;             // within-batch base point
  const int gp0 = bb * NN + ip0;                     // 4 points/block

  if (tid >= 64 && tid < 128) {  // stage q rows (bf16); overlaps knn below
    int e = tid - 64;
    int p = e >> 4, seg = e & 15;
    *(short8*)(q_ss + p * 128 + seg * 8) =
        *(const short8*)(qkv + (size_t)(gp0 + p) * 384 + seg * 8);
  }

  // ---- in-kernel KNN: wave w handles point ip0+w (identical to old kernel)
  {
    const float* px = pos_t + (size_t)bb * 3 * NN;
    const float* py = px + NN;
    const float* pz = py + NN;
    const int ip = ip0 + w;
    const float xi = px[ip], yi = py[ip], zi = pz[ip];
    const float sqi = xi * xi + yi * yi + zi * zi;
    float v[32];
#pragma unroll
    for (int t = 0; t < 32; ++t) {
      int j = t * 64 + lane;
      float xj = px[j], yj = py[j], zj = pz[j];
      float sqj = xj * xj + yj * yj + zj * zj;
      float dot = xi * xj + yi * yj + zi * zj;
      v[t] = sqi + sqj - 2.0f * dot;
    }
    int mynbr = 0;
    for (int s = 0; s < KNN; ++s) {
      float bv = 3.4e38f; int bj = 1 << 30;
#pragma unroll
      for (int t = 0; t < 32; ++t) {
        if (v[t] < bv) { bv = v[t]; bj = t * 64 + lane; }
      }
#pragma unroll
      for (int m = 1; m < 64; m <<= 1) {
        float ov = __shfl_xor(bv, m);
        int   oj = __shfl_xor(bj, m);
        if (ov < bv || (ov == bv && oj < bj)) { bv = ov; bj = oj; }
      }
      if (lane == s) mynbr = bj;
#pragma unroll
      for (int t = 0; t < 32; ++t)
        if (bj == t * 64 + lane) v[t] = 3.4e38f;
    }
    if (lane < 16) {   // wave-local rows w*16..w*16+15
      nbr_s[w * 16 + lane] = mynbr;
      relp_s[(w * 16 + lane) * 4 + 0] = xi - px[mynbr];
      relp_s[(w * 16 + lane) * 4 + 1] = yi - py[mynbr];
      relp_s[(w * 16 + lane) * 4 + 2] = zi - pz[mynbr];
    }
  }
  __syncthreads();   // nbr/relp/q_ss visible block-wide

  // ph = relu(bn(relp @ pos_w1 + b1)) -> t1_s (64 rows x 64 cols)
#pragma unroll
  for (int r2 = 0; r2 < 16; ++r2) {
    int e = tid + r2 * 256;
    int row = e >> 6, c = e & 63;
    float lin = relp_s[row * 4] * pos_w1[c] + relp_s[row * 4 + 1] * pos_w1[64 + c]
              + relp_s[row * 4 + 2] * pos_w1[128 + c];
    t1_s[row * 64 + (((c >> 3) ^ (row & 7)) << 3) + (c & 7)] =
        f2bf(fmaxf(lin * phsc[c] + phbi[c], 0.0f));
  }
  __syncthreads();

  // pe = ph @ pos_w2 (pos_b2 pre-folded into qkv q/v cols)
  floatx4 pe[2][4];
#pragma unroll
  for (int i = 0; i < 2; ++i)
#pragma unroll
    for (int jt = 0; jt < 4; ++jt) pe[i][jt] = (floatx4){0.f, 0.f, 0.f, 0.f};
#pragma unroll
  for (int ks = 0; ks < 2; ++ks) {
    short8 a8[2];
#pragma unroll
    for (int i = 0; i < 2; ++i) {
      int row = (wr * 2 + i) * 16 + cc;
      a8[i] = *(const short8*)(t1_s + row * 64 + (((ks * 4 + q) ^ (row & 7)) << 3));
    }
#pragma unroll
    for (int jt = 0; jt < 4; ++jt) {
      short8 b8 = *(const short8*)(pw2p + ((((wc * 4 + jt) * 2 + ks) * 64 + lane) << 3));
#pragma unroll
      for (int i = 0; i < 2; ++i)
        pe[i][jt] = __builtin_amdgcn_mfma_f32_16x16x32_bf16(a8[i], b8, pe[i][jt], 0, 0, 0);
    }
  }

  // preload q values for this thread's (row-tile, col) positions
  float qreg[2][4];
#pragma unroll
  for (int i = 0; i < 2; ++i)
#pragma unroll
    for (int jt = 0; jt < 4; ++jt)
      qreg[i][jt] = bf2f(q_ss[(wr * 2 + i) * 128 + (wc * 4 + jt) * 16 + cc]);

  // combine: a = q - k_g + pe -> av_s ; vpe = v_g + pe -> short-lived regs.
  floatx4 vpe[2][4];
#pragma unroll
  for (int i = 0; i < 2; ++i) {
    int rt = wr * 2 + i;
#pragma unroll
    for (int r = 0; r < 4; ++r) {
      int row = rt * 16 + q * 4 + r;
      const short* kv = qkv + ((size_t)bb * NN + nbr_s[row]) * 384;
      int sb = row * 128, sx = row & 15;
#pragma unroll
      for (int jt = 0; jt < 4; ++jt) {
        int col = (wc * 4 + jt) * 16 + cc;
        float pev = pe[i][jt][r];
        av_s[sb + (((col >> 3) ^ sx) << 3) + (col & 7)] =
            f2bf(qreg[i][jt] - bf2f(kv[128 + col]) + pev);
        vpe[i][jt][r] = bf2f(kv[256 + col]) + pev;
      }
    }
  }
  __syncthreads();   // av_s (=a) fully built; pe reads of t1_s complete

  // Hoist chunk-invariant A-fragments into registers (used every chunk).
  short8 af[2][4];
#pragma unroll
  for (int i = 0; i < 2; ++i) {
    int row = (wr * 2 + i) * 16 + cc;
#pragma unroll
    for (int ks = 0; ks < 4; ++ks)
      af[i][ks] = *(const short8*)(av_s + row * 128 + (((ks * 4 + q) ^ cc) << 3));
  }
  __syncthreads();   // all a-frags consumed; av_s reusable

  // Park vpe into av_s (thread-local slots; same thread reads them back).
#pragma unroll
  for (int i = 0; i < 2; ++i) {
    int rt = wr * 2 + i;
#pragma unroll
    for (int r = 0; r < 4; ++r) {
      int row = rt * 16 + q * 4 + r;
      int sb = row * 128, sx = row & 15;
#pragma unroll
      for (int jt = 0; jt < 4; ++jt) {
        int col = (wc * 4 + jt) * 16 + cc;
        av_s[sb + (((col >> 3) ^ sx) << 3) + (col & 7)] = f2bf(vpe[i][jt][r]);
      }
    }
  }

  floatx4 hacc[2][4];
#pragma unroll
  for (int i = 0; i < 2; ++i)
#pragma unroll
    for (int jt = 0; jt < 4; ++jt) hacc[i][jt] = (floatx4){0.f, 0.f, 0.f, 0.f};

  for (int ch = 0; ch < 8; ++ch) {
    // GEMM1 per col-tile: tacc[2] (8 acc regs) + single b8.
#pragma unroll
    for (int jt = 0; jt < 2; ++jt) {
      floatx4 tacc[2];
      tacc[0] = (floatx4){0.f, 0.f, 0.f, 0.f};
      tacc[1] = (floatx4){0.f, 0.f, 0.f, 0.f};
#pragma unroll
      for (int ks = 0; ks < 4; ++ks) {
        short8 b8 = *(const short8*)(w1p + ((((ch * 4 + wc * 2 + jt) * 4 + ks) * 64 + lane) << 3));
#pragma unroll
        for (int i = 0; i < 2; ++i)
          tacc[i] = __builtin_amdgcn_mfma_f32_16x16x32_bf16(af[i][ks], b8, tacc[i], 0, 0, 0);
      }
      // bn/relu -> t1_s (this col-tile, swizzled)
      int colL = (wc * 2 + jt) * 16 + cc;
      int colG = ch * 64 + colL;
      float sc = t1sc[colG], bi = t1bi[colG];
#pragma unroll
      for (int i = 0; i < 2; ++i)
#pragma unroll
        for (int r = 0; r < 4; ++r) {
          int row = (wr * 2 + i) * 16 + q * 4 + r;
          t1_s[row * 64 + (((colL >> 3) ^ (row & 7)) << 3) + (colL & 7)] =
              f2bf(fmaxf(tacc[i][r] * sc + bi, 0.0f));
        }
    }
    __syncthreads();   // t1 visible to all waves
    // GEMM2: hacc += t1 @ w2[ch*64 : +64, :]; B in 2 batches of 2.
#pragma unroll
    for (int ks = 0; ks < 2; ++ks) {
      short8 a8[2];
#pragma unroll
      for (int i = 0; i < 2; ++i) {
        int row = (wr * 2 + i) * 16 + cc;
        a8[i] = *(const short8*)(t1_s + row * 64 + (((ks * 4 + q) ^ (row & 7)) << 3));
      }
#pragma unroll
      for (int jh = 0; jh < 2; ++jh) {
        short8 b8[2];
#pragma unroll
        for (int j2 = 0; j2 < 2; ++j2)
          b8[j2] = *(const short8*)(w2p + ((((ch * 8 + wc * 4 + jh * 2 + j2) * 2 + ks) * 64 + lane) << 3));
#pragma unroll
        for (int i = 0; i < 2; ++i)
#pragma unroll
          for (int j2 = 0; j2 < 2; ++j2)
            hacc[i][jh * 2 + j2] = __builtin_amdgcn_mfma_f32_16x16x32_bf16(a8[i], b8[j2], hacc[i][jh * 2 + j2], 0, 0, 0);
      }
    }
    __syncthreads();   // all t1 reads done before next chunk overwrites
  }

  // softmax over the 16 neighbors per (point, channel) + aggregate
#pragma unroll
  for (int i = 0; i < 2; ++i) {
    int rt = wr * 2 + i;
#pragma unroll
    for (int jt = 0; jt < 4; ++jt) {
      int col = (wc * 4 + jt) * 16 + cc;
      float b2v = attn_b2[col];
      float v0[4], mx = -3.4e38f;
#pragma unroll
      for (int r = 0; r < 4; ++r) {
        v0[r] = (hacc[i][jt][r] + b2v) * SCALE;
        mx = fmaxf(mx, v0[r]);
      }
      mx = fmaxf(mx, __shfl_xor(mx, 16));
      mx = fmaxf(mx, __shfl_xor(mx, 32));
      float ex[4], sum = 0.f;
#pragma unroll
      for (int r = 0; r < 4; ++r) { ex[r] = __expf(v0[r] - mx); sum += ex[r]; }
      sum += __shfl_xor(sum, 16);
      sum += __shfl_xor(sum, 32);
      float inv = 1.0f / sum;
      float part = 0.f;
#pragma unroll
      for (int r = 0; r < 4; ++r) {
        int row = rt * 16 + q * 4 + r;
        int slot = row * 128 + (((col >> 3) ^ (row & 15)) << 3) + (col & 7);
        part += ex[r] * bf2f(av_s[slot]);
      }
      part += __shfl_xor(part, 16);
      part += __shfl_xor(part, 32);
      if (q == 0) agg[(size_t)(gp0 + rt) * DIM + col] = part * inv;
    }
  }
}

extern "C" void kernel_launch(void* const* d_in, const int* in_sizes, int n_in,
                              void* d_out, int out_size, void* d_ws, size_t ws_size,
                              hipStream_t stream)
{
  const float* ori_x    = (const float*)d_in[0];
  const float* pos      = (const float*)d_in[1];
  const float* w_in     = (const float*)d_in[2];
  const float* w_qkv    = (const float*)d_in[3];
  const float* w_out    = (const float*)d_in[4];
  const float* pos_w1   = (const float*)d_in[5];
  const float* pos_b1   = (const float*)d_in[6];
  const float* pos_bn_g = (const float*)d_in[7];
  const float* pos_bn_b = (const float*)d_in[8];
  const float* pos_bn_m = (const float*)d_in[9];
  const float* pos_bn_v = (const float*)d_in[10];
  const float* pos_w2   = (const float*)d_in[11];
  const float* pos_b2   = (const float*)d_in[12];
  const float* attn_w1  = (const float*)d_in[13];
  const float* attn_b1  = (const float*)d_in[14];
  const float* attn_bn_g = (const float*)d_in[15];
  const float* attn_bn_b = (const float*)d_in[16];
  const float* attn_bn_m = (const float*)d_in[17];
  const float* attn_bn_v = (const float*)d_in[18];
  const float* attn_w2  = (const float*)d_in[19];
  const float* attn_b2  = (const float*)d_in[20];
  float* out = (float*)d_out;

  float* agg  = (float*)d_ws;                          // [NPTS*128] f32; Wf aliases head
  float* Wf   = agg;                                   // [128*384] (consumed by pack)
  short* qkvb = (short*)(agg + (size_t)NPTS * DIM);    // [NPTS*384] bf16
  short* w1p  = qkvb + (size_t)NPTS * 3 * DIM;
  short* w2p  = w1p + 65536;
  short* pw2p = w2p + 65536;
  short* wfp  = pw2p + 8192;
  short* wop  = wfp + 49152;
  float* biasq = (float*)(wop + 16384);
  float* t1sc = biasq + 384;
  float* t1bi = t1sc + 512;
  float* phsc = t1bi + 512;
  float* phbi = phsc + 64;
  float* pos_t = phbi + 64;                            // [NB*3*NN]

  gemm_f32<<<dim3(2, 6), 256, 0, stream>>>(w_in, w_qkv, Wf, 128, 384, 128);
  pack_weights<<<998, 256, 0, stream>>>(attn_w1, attn_w2, pos_w2, Wf, w_out, pos,
      attn_b1, attn_bn_g, attn_bn_b, attn_bn_m, attn_bn_v,
      pos_b1, pos_bn_g, pos_bn_b, pos_bn_m, pos_bn_v, pos_b2,
      w1p, w2p, pw2p, wfp, wop, biasq, t1sc, t1bi, phsc, phbi, pos_t);
  gemm_in<<<dim3(NPTS / 64, 3), 256, 0, stream>>>(ori_x, wfp, biasq, qkvb);
  fused_attn<<<NPTS / 4, 256, 0, stream>>>(pos_t, qkvb,
      pos_w1, w1p, w2p, pw2p, t1sc, t1bi, phsc, phbi, attn_b2, agg);
  gemm_out<<<NPTS / 64, 256, 0, stream>>>(agg, wop, ori_x, out);
}